// Round 11
// baseline (196.530 us; speedup 1.0000x reference)
//
#include <hip/hip_runtime.h>
#include <math.h>

#define NSEQ 2048
#define EPSF 1e-8f
#define INV2R2 0.35355339059327373f
#define INVR2  0.7071067811865476f
#define NT 512           // kB: 8 waves. Grid=8 blocks on 256 CUs -> 1 block/CU always;
                         // launch_bounds(512,1) -> VGPR cap 256 (no spill), TLP unchanged.

// ---------- compile-time Leray conv taps ----------
// K = -0.5*sum M^i (50 Jacobi iters), LK = delta - 2nd-diff(K) (support |o|<=50).
// lk65: LK truncated to radius 32 (tail ~3e-6, validated r5/r6).
// lk2:  (LK*LK) truncated to radius 64 — exact double conv of untruncated LK.
//       Identity: up_{s+1} = up_s - 0.1*conv(LK2, upbar_s), so u is never needed.
struct TapsAll { float lk65[65]; float lk2[129]; };

constexpr TapsAll make_taps() {
  TapsAll t{};
  double K[99] = {};
  for (int j = -49; j <= 49; ++j) {
    int aj = j < 0 ? -j : j;
    double term = 1.0;
    for (int q = 0; q < aj; ++q) term *= 0.5;
    double sum = term;
    for (int i = aj + 2; i <= 49; i += 2) {
      int m = (i + j) / 2;
      term *= (double)((i - 1) * i) / (4.0 * (double)m * (double)(i - m));
      sum += term;
    }
    K[j + 49] = -0.5 * sum;
  }
  double LKd[101] = {};
  for (int o = -50; o <= 50; ++o) {
    double km1 = (o - 1 >= -49 && o - 1 <= 49) ? K[o - 1 + 49] : 0.0;
    double k0  = (o     >= -49 && o     <= 49) ? K[o + 49]     : 0.0;
    double kp1 = (o + 1 >= -49 && o + 1 <= 49) ? K[o + 1 + 49] : 0.0;
    LKd[o + 50] = ((o == 0) ? 1.0 : 0.0) - (kp1 - 2.0 * k0 + km1);
  }
  for (int o = -32; o <= 32; ++o) t.lk65[o + 32] = (float)LKd[o + 50];
  for (int o = -64; o <= 64; ++o) {
    double s = 0.0;
    int alo = (o - 50 > -50) ? o - 50 : -50;
    int ahi = (o + 50 <  50) ? o + 50 :  50;
    for (int a = alo; a <= ahi; ++a) s += LKd[a + 50] * LKd[o - a + 50];
    t.lk2[o + 64] = (float)s;
  }
  return t;
}
constexpr TapsAll TAPS = make_taps();

// ---------- reduction helpers (512 threads = 8 waves) ----------
__device__ __forceinline__ float wave_sum(float x) {
#pragma unroll
  for (int m = 1; m < 64; m <<= 1) x += __shfl_xor(x, m, 64);
  return x;
}
__device__ __forceinline__ float wave_max(float x) {
#pragma unroll
  for (int m = 1; m < 64; m <<= 1) x = fmaxf(x, __shfl_xor(x, m, 64));
  return x;
}
__device__ __forceinline__ float block_sum(float x, float* red, int tid, int& gen) {
  float w = wave_sum(x);
  int slot = (gen & 7) << 5; gen++;
  if ((tid & 63) == 0) red[slot + (tid >> 6)] = w;
  __syncthreads();
  float4 a = *(float4*)(red + slot), b = *(float4*)(red + slot + 4);
  return ((a.x + a.y) + (a.z + a.w)) + ((b.x + b.y) + (b.z + b.w));
}
__device__ __forceinline__ void block_sum2(float a, float b, float* red, int tid, int& gen,
                                           float& oa, float& ob) {
  float wa = wave_sum(a), wb = wave_sum(b);
  int slot = (gen & 7) << 5; gen++;
  if ((tid & 63) == 0) { int w = tid >> 6; red[slot + w] = wa; red[slot + 16 + w] = wb; }
  __syncthreads();
  float4 a0 = *(float4*)(red + slot),      a1 = *(float4*)(red + slot + 4);
  float4 b0 = *(float4*)(red + slot + 16), b1 = *(float4*)(red + slot + 20);
  oa = ((a0.x + a0.y) + (a0.z + a0.w)) + ((a1.x + a1.y) + (a1.z + a1.w));
  ob = ((b0.x + b0.y) + (b0.z + b0.w)) + ((b1.x + b1.y) + (b1.z + b1.w));
}
__device__ __forceinline__ float sgnf(float x) {
  return (x > 0.f) ? 1.f : ((x < 0.f) ? -1.f : 0.f);
}

// ---------- 65-tap conv (radius 32): regs in, regs out, single cb buffer ----------
// Caller guarantees >=1 block barrier since last reads of cb.
__device__ __forceinline__ void conv65(const float in[4], float acc[4],
                                       float* __restrict__ cb, int tid) {
  *(float4*)(cb + (tid << 2)) = make_float4(in[0], in[1], in[2], in[3]);
  __syncthreads();
  const int base = tid << 2;
  acc[0] = 0.f; acc[1] = 0.f; acc[2] = 0.f; acc[3] = 0.f;
#pragma unroll
  for (int m = 0; m < 17; ++m) {
    const int idx = (base - 32 + 4 * m) & (NSEQ - 1);
    const float4 c4 = *(const float4*)(cb + idx);
    const float cv[4] = {c4.x, c4.y, c4.z, c4.w};
#pragma unroll
    for (int jj = 0; jj < 4; ++jj) {
      const int d = 4 * m + jj;
#pragma unroll
      for (int j = 0; j < 4; ++j) {
        const int o = d - 32 - j;
        if (o >= -32 && o <= 32) acc[j] = fmaf(TAPS.lk65[o + 32], cv[jj], acc[j]);
      }
    }
  }
}

// ---------- 129-tap conv (radius 64, LK^2): one per MPC step ----------
__device__ __forceinline__ void conv129(const float in[4], float acc[4],
                                        float* __restrict__ cb, int tid) {
  *(float4*)(cb + (tid << 2)) = make_float4(in[0], in[1], in[2], in[3]);
  __syncthreads();
  const int base = tid << 2;
  acc[0] = 0.f; acc[1] = 0.f; acc[2] = 0.f; acc[3] = 0.f;
#pragma unroll
  for (int m = 0; m < 33; ++m) {
    const int idx = (base - 64 + 4 * m) & (NSEQ - 1);
    const float4 c4 = *(const float4*)(cb + idx);
    const float cv[4] = {c4.x, c4.y, c4.z, c4.w};
#pragma unroll
    for (int jj = 0; jj < 4; ++jj) {
      const int d = 4 * m + jj;
#pragma unroll
      for (int j = 0; j < 4; ++j) {
        const int o = d - 64 - j;
        if (o >= -64 && o <= 64) acc[j] = fmaf(TAPS.lk2[o + 64], cv[jj], acc[j]);
      }
    }
  }
}

// ---------- kernel A: rho_unscaled (L2 of DWT rows) + per_token ----------
__global__ __launch_bounds__(256) void kA(const float* __restrict__ x,
                                          const float* __restrict__ wv,
                                          float* __restrict__ rho_us,
                                          float* __restrict__ pt) {
  const int blk = blockIdx.x;
  const int b = blk >> 8;
  const int g = blk & 255;
  const float* xb = x + (((size_t)b * NSEQ) + (size_t)g * 8) * 2048;
  const int tid = threadIdx.x;
  float sq[8] = {0.f, 0.f, 0.f, 0.f, 0.f, 0.f, 0.f, 0.f};
  float pp[8] = {0.f, 0.f, 0.f, 0.f, 0.f, 0.f, 0.f, 0.f};
  for (int c = tid * 4; c < 2048; c += 1024) {
    float4 w4 = *(const float4*)(wv + c);
    float wj[4] = {w4.x, w4.y, w4.z, w4.w};
    float xv[8][4];
#pragma unroll
    for (int r = 0; r < 8; ++r) {
      float4 t = *(const float4*)(xb + (size_t)r * 2048 + c);
      xv[r][0] = t.x; xv[r][1] = t.y; xv[r][2] = t.z; xv[r][3] = t.w;
    }
#pragma unroll
    for (int j = 0; j < 4; ++j) {
      float x0 = xv[0][j], x1 = xv[1][j], x2 = xv[2][j], x3 = xv[3][j];
      float x4 = xv[4][j], x5 = xv[5][j], x6 = xv[6][j], x7 = xv[7][j];
      float t01 = x0 + x1, t23 = x2 + x3, t45 = x4 + x5, t67 = x6 + x7;
      float a = t01 + t23, bb = t45 + t67;
      float c3 = a + bb, d3 = a - bb, d2a = t01 - t23, d2b = t45 - t67;
      float d10 = x0 - x1, d11 = x2 - x3, d12 = x4 - x5, d13 = x6 - x7;
      sq[0] += c3 * c3;  sq[1] += d3 * d3;  sq[2] += d2a * d2a; sq[3] += d2b * d2b;
      sq[4] += d10 * d10; sq[5] += d11 * d11; sq[6] += d12 * d12; sq[7] += d13 * d13;
      float w = wj[j];
      pp[0] += x0 * w; pp[1] += x1 * w; pp[2] += x2 * w; pp[3] += x3 * w;
      pp[4] += x4 * w; pp[5] += x5 * w; pp[6] += x6 * w; pp[7] += x7 * w;
    }
  }
  __shared__ float sred[4][16];
  float vals[16];
#pragma unroll
  for (int q = 0; q < 8; ++q) vals[q] = sq[q];
#pragma unroll
  for (int q = 0; q < 8; ++q) vals[8 + q] = pp[q];
#pragma unroll
  for (int q = 0; q < 16; ++q) vals[q] = wave_sum(vals[q]);
  int lane = tid & 63, wid = tid >> 6;
  if (lane == 0) {
#pragma unroll
    for (int q = 0; q < 16; ++q) sred[wid][q] = vals[q];
  }
  __syncthreads();
  if (tid < 16) {
    float s = sred[0][tid] + sred[1][tid] + sred[2][tid] + sred[3][tid];
    if (tid < 8) {
      float scale = (tid < 2) ? 0.125f : ((tid < 4) ? 0.25f : 0.5f);
      int pos = (tid == 0) ? g : (tid == 1) ? (256 + g)
               : (tid < 4) ? (512 + 2 * g + (tid - 2)) : (1024 + 4 * g + (tid - 4));
      rho_us[b * NSEQ + pos] = sqrtf(s * scale);
    } else {
      pt[b * NSEQ + 8 * g + (tid - 8)] = s;
    }
  }
}

// ---------- kernel B: serial dynamics; 512 threads, 4 contiguous elems/thread ----------
__global__ __launch_bounds__(NT, 1) void kB(const float* __restrict__ rho_us,
                                            const float* __restrict__ pt,
                                            const float* __restrict__ phi,
                                            float* __restrict__ rho_f) {
  __shared__ float cb[NSEQ];                    // conv staging (single buffer)
  __shared__ float vE0[NT];
  __shared__ float rhoE0[NT], rhoE3[NT];
  __shared__ float upE3[NT];
  __shared__ float yE0[3][NT], yE3[3][NT];
  __shared__ float4 pairE[2][NT];               // (sgw0,sg0,sgw3,sg3), by h-parity
  __shared__ float red[256];
  __shared__ float red2[8];

  const int tid = threadIdx.x;
  const int b = blockIdx.x;
  const int tm1 = (tid - 1) & (NT - 1);
  const int tp1 = (tid + 1) & (NT - 1);
  int gen = 0;
  const float CFL_ = 0.4f;

  float4 phv = *(const float4*)(phi + 4 * tid);
  float phir[4] = {phv.x, phv.y, phv.z, phv.w};

  // ---- v = normalize(|dwt1d(per_token)| * sqrt(D)) ----
  float v_r[4]; float vp4c;
  {
    const float* ptb = pt + b * NSEQ;
    float vl[4]; float part = 0.f;
#pragma unroll
    for (int j = 0; j < 4; ++j) {
      float c;
      if (tid < 64) {
        int r = (4 * tid + j) * 8;
        float t01 = ptb[r] + ptb[r+1], t23 = ptb[r+2] + ptb[r+3];
        float t45 = ptb[r+4] + ptb[r+5], t67 = ptb[r+6] + ptb[r+7];
        c = ((t01 + t23) + (t45 + t67)) * INV2R2;
      } else if (tid < 128) {
        int r = (4 * (tid - 64) + j) * 8;
        float t01 = ptb[r] + ptb[r+1], t23 = ptb[r+2] + ptb[r+3];
        float t45 = ptb[r+4] + ptb[r+5], t67 = ptb[r+6] + ptb[r+7];
        c = ((t01 + t23) - (t45 + t67)) * INV2R2;
      } else if (tid < 256) {
        int r = (4 * (tid - 128) + j) * 4;
        c = ((ptb[r] + ptb[r+1]) - (ptb[r+2] + ptb[r+3])) * 0.5f;
      } else {
        int r = (4 * (tid - 256) + j) * 2;
        c = (ptb[r] - ptb[r+1]) * INVR2;
      }
      float val = sqrtf(2048.0f * c * c) + EPSF;
      vl[j] = val; part += val;
    }
    float sv = block_sum(part, red, tid, gen);
    float inv = 1.0f / sv;
#pragma unroll
    for (int j = 0; j < 4; ++j) v_r[j] = vl[j] * inv;
    vE0[tid] = v_r[0];
  }
  // ---- rho = normalize(rho_us) ----
  float rho_r[4];
  {
    float4 rv = *(const float4*)(rho_us + b * NSEQ + 4 * tid);
    float rl[4] = {rv.x + EPSF, rv.y + EPSF, rv.z + EPSF, rv.w + EPSF};
    float part = rl[0] + rl[1] + rl[2] + rl[3];
    float sr = block_sum(part, red, tid, gen);   // barrier publishes vE0
    float inv = 1.f / sr;
#pragma unroll
    for (int j = 0; j < 4; ++j) rho_r[j] = rl[j] * inv;
  }
  vp4c = vE0[tp1];   // v never changes; cache once

  // ---- up0 = leray(grad1(v)) : computed ONCE, reused at every outer k ----
  float up_r[4], up0_r[4];
  float mx, mx0, um1c, um10;
  {
    float u0[4] = {v_r[1] - v_r[0], v_r[2] - v_r[1], v_r[3] - v_r[2], vp4c - v_r[3]};
    conv65(u0, up_r, cb, tid);
    upE3[tid] = up_r[3];
    float mm = fmaxf(fmaxf(fabsf(up_r[0]), fabsf(up_r[1])),
                     fmaxf(fabsf(up_r[2]), fabsf(up_r[3])));
    mm = wave_max(mm);
    if ((tid & 63) == 0) red2[tid >> 6] = mm;
    __syncthreads();
    float4 r2a = *(float4*)(red2), r2b = *(float4*)(red2 + 4);
    mx = fmaxf(fmaxf(fmaxf(r2a.x, r2a.y), fmaxf(r2a.z, r2a.w)),
               fmaxf(fmaxf(r2b.x, r2b.y), fmaxf(r2b.z, r2b.w)));
    um1c = upE3[tm1];
#pragma unroll
    for (int j = 0; j < 4; ++j) up0_r[j] = up_r[j];
    mx0 = mx; um10 = um1c;
  }

  for (int k = 0; k < 3; ++k) {
    // ---- reaction ----
    {
      float tl[4]; float part = 0.f;
#pragma unroll
      for (int j = 0; j < 4; ++j) {
        float r = rho_r[j];
        float t = r * expf(-0.1f * (phir[j] + logf(r)));
        float t2 = fabsf(t) + EPSF;
        tl[j] = t2; part += t2;
      }
      float s = block_sum(part, red, tid, gen);
      float inv = 1.f / s;
#pragma unroll
      for (int j = 0; j < 4; ++j) rho_r[j] = tl[j] * inv;
      rhoE0[tid] = rho_r[0]; rhoE3[tid] = rho_r[3];
    }
    __syncthreads();                       // publish rhoE
    const float rhom1 = rhoE3[tm1], rhop4 = rhoE0[tp1];  // constant over the 5 steps
    if (k > 0) {                           // u = grad1(v) identical every k -> reuse up0
#pragma unroll
      for (int j = 0; j < 4; ++j) up_r[j] = up0_r[j];
      mx = mx0; um1c = um10;
    }

    float y_r[4][4], ym1c[3], yp4c2[3];
    for (int step = 0; step < 5; ++step) {
      float dt = CFL_ / (mx + EPSF);
      // ---- forward rollout (ntie in h=0, cost-dot in h=3, passA(3) mirrored) ----
      float sarr[4]; float spv = 1.f; float ntie = 1.f, dot = 0.f;
#pragma unroll
      for (int h = 0; h < 4; ++h) {
        float invp = 1.f / spv;
        if (h >= 1) { ym1c[h-1] = yE3[h-1][tm1]; yp4c2[h-1] = yE0[h-1][tp1]; }
        float rr[6];
        if (h == 0) {
          rr[0] = rhom1; rr[1] = rho_r[0]; rr[2] = rho_r[1];
          rr[3] = rho_r[2]; rr[4] = rho_r[3]; rr[5] = rhop4;
        } else {
          rr[0] = (fabsf(ym1c[h-1]) + EPSF) * invp;
#pragma unroll
          for (int j = 0; j < 4; ++j) rr[j+1] = (fabsf(y_r[h-1][j]) + EPSF) * invp;
          rr[5] = (fabsf(yp4c2[h-1]) + EPSF) * invp;
        }
        float part2 = 0.f, aux = 0.f;
#pragma unroll
        for (int j = 0; j < 4; ++j) {
          float ri = rr[j+1], rim1 = rr[j], rip1 = rr[j+2];
          float ui = up_r[j], um = j ? up_r[j-1] : um1c;
          float Fi = ui > 0.f ? ui * ri : ui * rip1;
          float Fm = um > 0.f ? um * rim1 : um * ri;
          float yv = ri - dt * (Fi - Fm);
          y_r[h][j] = yv;
          float ayv = fabsf(yv) + EPSF;
          part2 += ayv;
          if (h == 0) aux += (fabsf(ui) == mx) ? 1.f : 0.f;
          if (h == 3) aux += (1.f - v_r[j]) * 0.125f * ayv;
        }
        if (h < 3) { yE0[h][tid] = y_r[h][0]; yE3[h][tid] = y_r[h][3]; }
        if (h == 3) {
          float sg0 = sgnf(y_r[3][0]), sg3 = sgnf(y_r[3][3]);
          pairE[1][tid] = make_float4(sg0 * (1.f - v_r[0]) * 0.125f, sg0,
                                      sg3 * (1.f - v_r[3]) * 0.125f, sg3);
        }
        if (h == 0) { float o1, o2; block_sum2(part2, aux, red, tid, gen, o1, o2); sarr[0] = o1; ntie = o2; }
        else if (h == 3) { float o1, o2; block_sum2(part2, aux, red, tid, gen, o1, o2); sarr[3] = o1; dot = o2 / o1; }
        else sarr[h] = block_sum(part2, red, tid, gen);
        spv = sarr[h];
      }
      // ---- backward (passA folded into dot barriers via pairE mirrors) ----
      float wreg[4], upbar[4];
#pragma unroll
      for (int j = 0; j < 4; ++j) { wreg[j] = (1.f - v_r[j]) * 0.125f; upbar[j] = 0.f; }
      float dtb_part = 0.f;
#pragma unroll
      for (int h = 3; h >= 0; --h) {
        float invst = 1.f / sarr[h];
        float invp = (h > 0) ? 1.f / sarr[h-1] : 0.f;
        const int bo = h & 1;
        float yb_r[4];
#pragma unroll
        for (int j = 0; j < 4; ++j)
          yb_r[j] = sgnf(y_r[h][j]) * (wreg[j] - dot) * invst;
        float4 pm = pairE[bo][tm1], pp = pairE[bo][tp1];
        float ybm1 = (pm.z - dot * pm.w) * invst;
        float ybp4 = (pp.x - dot * pp.y) * invst;
        float rr[6];
        if (h == 0) {
          rr[0] = rhom1; rr[1] = rho_r[0]; rr[2] = rho_r[1];
          rr[3] = rho_r[2]; rr[4] = rho_r[3]; rr[5] = rhop4;
        } else {
          rr[0] = (fabsf(ym1c[h-1]) + EPSF) * invp;
#pragma unroll
          for (int j = 0; j < 4; ++j) rr[j+1] = (fabsf(y_r[h-1][j]) + EPSF) * invp;
          rr[5] = (fabsf(yp4c2[h-1]) + EPSF) * invp;
        }
        float dotn = 0.f;
#pragma unroll
        for (int j = 0; j < 4; ++j) {
          float ri = rr[j+1], rim1 = rr[j], rip1 = rr[j+2];
          float ui = up_r[j], um = j ? up_r[j-1] : um1c;
          float ybi = yb_r[j];
          float ybm = j ? yb_r[j-1] : ybm1;
          float ybp = (j < 3) ? yb_r[j+1] : ybp4;
          float Fbi = dt * (ybp - ybi);
          float Fbm = dt * (ybi - ybm);
          float wn = ybi;
          if (ui > 0.f)    wn += Fbi * ui;
          if (!(um > 0.f)) wn += Fbm * um;
          upbar[j] += Fbi * (ui > 0.f ? ri : rip1);
          float Fi = ui > 0.f ? ui * ri : ui * rip1;
          float Fm = um > 0.f ? um * rim1 : um * ri;
          dtb_part -= ybi * (Fi - Fm);
          if (h > 0) dotn += wn * ri;
          wreg[j] = wn;
        }
        if (h > 0) {
          float sgA = sgnf(y_r[h-1][0]), sgB = sgnf(y_r[h-1][3]);
          pairE[(h - 1) & 1][tid] = make_float4(sgA * wreg[0], sgA, sgB * wreg[3], sgB);
          dot = block_sum(dotn, red, tid, gen);
        }
      }
      float dtbar = block_sum(dtb_part, red, tid, gen);
      float md = mx + EPSF;
      float mbar = dtbar * (-CFL_ / (md * md));
      float tiesc = mbar / ntie;
#pragma unroll
      for (int j = 0; j < 4; ++j) {
        float ui = up_r[j];
        if (fabsf(ui) == mx) upbar[j] += tiesc * sgnf(ui);
      }
      // ---- up -= 0.1 * conv(LK^2, upbar); epilogue folds max + edge publish ----
      float accv[4];
      conv129(upbar, accv, cb, tid);
#pragma unroll
      for (int j = 0; j < 4; ++j) up_r[j] -= 0.1f * accv[j];
      upE3[tid] = up_r[3];
      {
        float mm = fmaxf(fmaxf(fabsf(up_r[0]), fabsf(up_r[1])),
                         fmaxf(fabsf(up_r[2]), fabsf(up_r[3])));
        mm = wave_max(mm);
        if ((tid & 63) == 0) red2[tid >> 6] = mm;
      }
      __syncthreads();
      float4 r2a = *(float4*)(red2), r2b = *(float4*)(red2 + 4);
      mx = fmaxf(fmaxf(fmaxf(r2a.x, r2a.y), fmaxf(r2a.z, r2a.w)),
                 fmaxf(fmaxf(r2b.x, r2b.y), fmaxf(r2b.z, r2b.w)));
      um1c = upE3[tm1];
    }
    // ---- outer: up already = leray(u_final); advect + normalize ----
    float dt = CFL_ / (mx + EPSF);
    float kap = (k == 0) ? 0.01f : ((k == 1) ? 0.005f : 0.0f);
    float rr[6];
    rr[0] = rhom1; rr[1] = rho_r[0]; rr[2] = rho_r[1];
    rr[3] = rho_r[2]; rr[4] = rho_r[3]; rr[5] = rhop4;
    float ylc[4]; float p2 = 0.f;
#pragma unroll
    for (int j = 0; j < 4; ++j) {
      float ri = rr[j+1], rim1 = rr[j], rip1 = rr[j+2];
      float ui = up_r[j], um = j ? up_r[j-1] : um1c;
      float Fi = ui > 0.f ? ui * ri : ui * rip1;
      float Fm = um > 0.f ? um * rim1 : um * ri;
      float yv = ri - dt * (Fi - Fm) + kap * dt * (rip1 + rim1 - 2.f * ri);
      ylc[j] = yv; p2 += fabsf(yv) + EPSF;
    }
    float s = block_sum(p2, red, tid, gen);
    float inv = 1.f / s;
#pragma unroll
    for (int j = 0; j < 4; ++j) rho_r[j] = (fabsf(ylc[j]) + EPSF) * inv;
  }
  // ---- final: rho_f = (rho + 0.1 v)/sum ----
  {
    float fl[4]; float part = 0.f;
#pragma unroll
    for (int j = 0; j < 4; ++j) {
      float f = rho_r[j] + 0.1f * v_r[j];
      fl[j] = f; part += f;
    }
    float s = block_sum(part, red, tid, gen);
    float inv = 1.f / s;
    *(float4*)(rho_f + b * NSEQ + 4 * tid) =
        make_float4(fl[0] * inv, fl[1] * inv, fl[2] * inv, fl[3] * inv);
  }
}

// ---------- kernel C: out = IDWT3(rho_f[:,:,None] * band_w[BAND_IDX]) ----------
__global__ __launch_bounds__(256) void kC(const float* __restrict__ rho_f,
                                          const float* __restrict__ bw,
                                          float* __restrict__ out) {
  const int blk = blockIdx.x;
  const int b = blk >> 8;
  const int g = blk & 255;
  __shared__ float q[8];
  if (threadIdx.x < 8) {
    int t = threadIdx.x;
    const float* rb = rho_f + b * NSEQ;
    float val;
    if (t == 0)      val = rb[g] * INV2R2;
    else if (t == 1) val = rb[256 + g] * INV2R2;
    else if (t < 4)  val = rb[512 + 2 * g + (t - 2)] * 0.5f;
    else             val = rb[1024 + 4 * g + (t - 4)] * INVR2;
    q[t] = val;
  }
  __syncthreads();
  float* ob = out + (((size_t)b * NSEQ) + (size_t)g * 8) * 2048;
  for (int c = threadIdx.x * 4; c < 2048; c += 1024) {
    float4 B0 = *(const float4*)(bw + c);
    float4 B1 = *(const float4*)(bw + 2048 + c);
    float4 B2 = *(const float4*)(bw + 4096 + c);
    float4 B3 = *(const float4*)(bw + 6144 + c);
    float b0[4] = {B0.x, B0.y, B0.z, B0.w};
    float b1[4] = {B1.x, B1.y, B1.z, B1.w};
    float b2[4] = {B2.x, B2.y, B2.z, B2.w};
    float b3[4] = {B3.x, B3.y, B3.z, B3.w};
    float o[8][4];
#pragma unroll
    for (int cc = 0; cc < 4; ++cc) {
      float pa = q[0] * b0[cc], pd3 = q[1] * b1[cc];
      float p2a = q[2] * b2[cc], p2b = q[3] * b2[cc];
      float e0 = pa + pd3, e1 = pa - pd3;
      float f0 = e0 + p2a, f1 = e0 - p2a, f2 = e1 + p2b, f3 = e1 - p2b;
      float g0 = q[4] * b3[cc], g1 = q[5] * b3[cc], g2 = q[6] * b3[cc], g3 = q[7] * b3[cc];
      o[0][cc] = f0 + g0; o[1][cc] = f0 - g0;
      o[2][cc] = f1 + g1; o[3][cc] = f1 - g1;
      o[4][cc] = f2 + g2; o[5][cc] = f2 - g2;
      o[6][cc] = f3 + g3; o[7][cc] = f3 - g3;
    }
#pragma unroll
    for (int j = 0; j < 8; ++j) {
      float4 t = make_float4(o[j][0], o[j][1], o[j][2], o[j][3]);
      *(float4*)(ob + (size_t)j * 2048 + c) = t;
    }
  }
}

extern "C" void kernel_launch(void* const* d_in, const int* in_sizes, int n_in,
                              void* d_out, int out_size, void* d_ws, size_t ws_size,
                              hipStream_t stream) {
  (void)in_sizes; (void)n_in; (void)out_size; (void)ws_size;
  const float* x   = (const float*)d_in[0];
  const float* wv  = (const float*)d_in[1];
  const float* phi = (const float*)d_in[2];
  const float* bw  = (const float*)d_in[3];
  float* out = (float*)d_out;
  float* rho_us = (float*)d_ws;
  float* pt     = rho_us + 8 * NSEQ;
  float* rho_f  = pt + 8 * NSEQ;

  kA<<<dim3(2048), dim3(256), 0, stream>>>(x, wv, rho_us, pt);
  kB<<<dim3(8), dim3(NT), 0, stream>>>(rho_us, pt, phi, rho_f);
  kC<<<dim3(2048), dim3(256), 0, stream>>>(rho_f, bw, out);
}

// Round 12
// 179.558 us; speedup vs baseline: 1.0945x; 1.0945x over previous
//
#include <hip/hip_runtime.h>
#include <math.h>

#define NSEQ 2048
#define EPSF 1e-8f
#define INV2R2 0.35355339059327373f
#define INVR2  0.7071067811865476f
#define NT 512   // HW law (r2/r5/r8/r9/r11): VGPR cap = 65536/B. 512 threads -> 128 regs.

// ---------- compile-time Leray conv taps ----------
// K = -0.5*sum M^i (50 Jacobi iters), LK = delta - 2nd-diff(K) (support |o|<=50).
// lk65: LK truncated to radius 32 (tail ~3e-6, validated r5/r6).
// lk2:  (LK*LK) truncated to radius 64 — exact double conv of untruncated LK.
//       Identity: up_{s+1} = up_s - 0.1*conv(LK2, upbar_s), so u is never needed.
struct TapsAll { float lk65[65]; float lk2[129]; };

constexpr TapsAll make_taps() {
  TapsAll t{};
  double K[99] = {};
  for (int j = -49; j <= 49; ++j) {
    int aj = j < 0 ? -j : j;
    double term = 1.0;
    for (int q = 0; q < aj; ++q) term *= 0.5;
    double sum = term;
    for (int i = aj + 2; i <= 49; i += 2) {
      int m = (i + j) / 2;
      term *= (double)((i - 1) * i) / (4.0 * (double)m * (double)(i - m));
      sum += term;
    }
    K[j + 49] = -0.5 * sum;
  }
  double LKd[101] = {};
  for (int o = -50; o <= 50; ++o) {
    double km1 = (o - 1 >= -49 && o - 1 <= 49) ? K[o - 1 + 49] : 0.0;
    double k0  = (o     >= -49 && o     <= 49) ? K[o + 49]     : 0.0;
    double kp1 = (o + 1 >= -49 && o + 1 <= 49) ? K[o + 1 + 49] : 0.0;
    LKd[o + 50] = ((o == 0) ? 1.0 : 0.0) - (kp1 - 2.0 * k0 + km1);
  }
  for (int o = -32; o <= 32; ++o) t.lk65[o + 32] = (float)LKd[o + 50];
  for (int o = -64; o <= 64; ++o) {
    double s = 0.0;
    int alo = (o - 50 > -50) ? o - 50 : -50;
    int ahi = (o + 50 <  50) ? o + 50 :  50;
    for (int a = alo; a <= ahi; ++a) s += LKd[a + 50] * LKd[o - a + 50];
    t.lk2[o + 64] = (float)s;
  }
  return t;
}
constexpr TapsAll TAPS = make_taps();

// ---------- uniform-scalar pin: value identical across lanes -> SGPR ----------
__device__ __forceinline__ float rfl(float x) {
  return __int_as_float(__builtin_amdgcn_readfirstlane(__float_as_int(x)));
}

// ---------- reduction helpers (512 threads = 8 waves) ----------
__device__ __forceinline__ float wave_sum(float x) {
#pragma unroll
  for (int m = 1; m < 64; m <<= 1) x += __shfl_xor(x, m, 64);
  return x;
}
__device__ __forceinline__ float wave_max(float x) {
#pragma unroll
  for (int m = 1; m < 64; m <<= 1) x = fmaxf(x, __shfl_xor(x, m, 64));
  return x;
}
__device__ __forceinline__ float block_sum(float x, float* red, int tid, int& gen) {
  float w = wave_sum(x);
  int slot = (gen & 7) << 5; gen++;
  if ((tid & 63) == 0) red[slot + (tid >> 6)] = w;
  __syncthreads();
  float4 a = *(float4*)(red + slot), b = *(float4*)(red + slot + 4);
  return rfl(((a.x + a.y) + (a.z + a.w)) + ((b.x + b.y) + (b.z + b.w)));
}
__device__ __forceinline__ void block_sum2(float a, float b, float* red, int tid, int& gen,
                                           float& oa, float& ob) {
  float wa = wave_sum(a), wb = wave_sum(b);
  int slot = (gen & 7) << 5; gen++;
  if ((tid & 63) == 0) { int w = tid >> 6; red[slot + w] = wa; red[slot + 16 + w] = wb; }
  __syncthreads();
  float4 a0 = *(float4*)(red + slot),      a1 = *(float4*)(red + slot + 4);
  float4 b0 = *(float4*)(red + slot + 16), b1 = *(float4*)(red + slot + 20);
  oa = rfl(((a0.x + a0.y) + (a0.z + a0.w)) + ((a1.x + a1.y) + (a1.z + a1.w)));
  ob = rfl(((b0.x + b0.y) + (b0.z + b0.w)) + ((b1.x + b1.y) + (b1.z + b1.w)));
}
__device__ __forceinline__ float sgnf(float x) {
  return (x > 0.f) ? 1.f : ((x < 0.f) ? -1.f : 0.f);
}

// ---------- 65-tap conv (radius 32): regs in, regs out, single cb buffer ----------
__device__ __forceinline__ void conv65(const float in[4], float acc[4],
                                       float* __restrict__ cb, int tid) {
  *(float4*)(cb + (tid << 2)) = make_float4(in[0], in[1], in[2], in[3]);
  __syncthreads();
  const int base = tid << 2;
  acc[0] = 0.f; acc[1] = 0.f; acc[2] = 0.f; acc[3] = 0.f;
#pragma unroll
  for (int m = 0; m < 17; ++m) {
    const int idx = (base - 32 + 4 * m) & (NSEQ - 1);
    const float4 c4 = *(const float4*)(cb + idx);
    const float cv[4] = {c4.x, c4.y, c4.z, c4.w};
#pragma unroll
    for (int jj = 0; jj < 4; ++jj) {
      const int d = 4 * m + jj;
#pragma unroll
      for (int j = 0; j < 4; ++j) {
        const int o = d - 32 - j;
        if (o >= -32 && o <= 32) acc[j] = fmaf(TAPS.lk65[o + 32], cv[jj], acc[j]);
      }
    }
  }
}

// ---------- 129-tap conv (radius 64, LK^2): one per MPC step ----------
__device__ __forceinline__ void conv129(const float in[4], float acc[4],
                                        float* __restrict__ cb, int tid) {
  *(float4*)(cb + (tid << 2)) = make_float4(in[0], in[1], in[2], in[3]);
  __syncthreads();
  const int base = tid << 2;
  acc[0] = 0.f; acc[1] = 0.f; acc[2] = 0.f; acc[3] = 0.f;
#pragma unroll
  for (int m = 0; m < 33; ++m) {
    const int idx = (base - 64 + 4 * m) & (NSEQ - 1);
    const float4 c4 = *(const float4*)(cb + idx);
    const float cv[4] = {c4.x, c4.y, c4.z, c4.w};
#pragma unroll
    for (int jj = 0; jj < 4; ++jj) {
      const int d = 4 * m + jj;
#pragma unroll
      for (int j = 0; j < 4; ++j) {
        const int o = d - 64 - j;
        if (o >= -64 && o <= 64) acc[j] = fmaf(TAPS.lk2[o + 64], cv[jj], acc[j]);
      }
    }
  }
}

// ---------- kernel A: rho_unscaled (L2 of DWT rows) + per_token ----------
__global__ __launch_bounds__(256) void kA(const float* __restrict__ x,
                                          const float* __restrict__ wv,
                                          float* __restrict__ rho_us,
                                          float* __restrict__ pt) {
  const int blk = blockIdx.x;
  const int b = blk >> 8;
  const int g = blk & 255;
  const float* xb = x + (((size_t)b * NSEQ) + (size_t)g * 8) * 2048;
  const int tid = threadIdx.x;
  float sq[8] = {0.f, 0.f, 0.f, 0.f, 0.f, 0.f, 0.f, 0.f};
  float pp[8] = {0.f, 0.f, 0.f, 0.f, 0.f, 0.f, 0.f, 0.f};
  for (int c = tid * 4; c < 2048; c += 1024) {
    float4 w4 = *(const float4*)(wv + c);
    float wj[4] = {w4.x, w4.y, w4.z, w4.w};
    float xv[8][4];
#pragma unroll
    for (int r = 0; r < 8; ++r) {
      float4 t = *(const float4*)(xb + (size_t)r * 2048 + c);
      xv[r][0] = t.x; xv[r][1] = t.y; xv[r][2] = t.z; xv[r][3] = t.w;
    }
#pragma unroll
    for (int j = 0; j < 4; ++j) {
      float x0 = xv[0][j], x1 = xv[1][j], x2 = xv[2][j], x3 = xv[3][j];
      float x4 = xv[4][j], x5 = xv[5][j], x6 = xv[6][j], x7 = xv[7][j];
      float t01 = x0 + x1, t23 = x2 + x3, t45 = x4 + x5, t67 = x6 + x7;
      float a = t01 + t23, bb = t45 + t67;
      float c3 = a + bb, d3 = a - bb, d2a = t01 - t23, d2b = t45 - t67;
      float d10 = x0 - x1, d11 = x2 - x3, d12 = x4 - x5, d13 = x6 - x7;
      sq[0] += c3 * c3;  sq[1] += d3 * d3;  sq[2] += d2a * d2a; sq[3] += d2b * d2b;
      sq[4] += d10 * d10; sq[5] += d11 * d11; sq[6] += d12 * d12; sq[7] += d13 * d13;
      float w = wj[j];
      pp[0] += x0 * w; pp[1] += x1 * w; pp[2] += x2 * w; pp[3] += x3 * w;
      pp[4] += x4 * w; pp[5] += x5 * w; pp[6] += x6 * w; pp[7] += x7 * w;
    }
  }
  __shared__ float sred[4][16];
  float vals[16];
#pragma unroll
  for (int q = 0; q < 8; ++q) vals[q] = sq[q];
#pragma unroll
  for (int q = 0; q < 8; ++q) vals[8 + q] = pp[q];
#pragma unroll
  for (int q = 0; q < 16; ++q) vals[q] = wave_sum(vals[q]);
  int lane = tid & 63, wid = tid >> 6;
  if (lane == 0) {
#pragma unroll
    for (int q = 0; q < 16; ++q) sred[wid][q] = vals[q];
  }
  __syncthreads();
  if (tid < 16) {
    float s = sred[0][tid] + sred[1][tid] + sred[2][tid] + sred[3][tid];
    if (tid < 8) {
      float scale = (tid < 2) ? 0.125f : ((tid < 4) ? 0.25f : 0.5f);
      int pos = (tid == 0) ? g : (tid == 1) ? (256 + g)
               : (tid < 4) ? (512 + 2 * g + (tid - 2)) : (1024 + 4 * g + (tid - 4));
      rho_us[b * NSEQ + pos] = sqrtf(s * scale);
    } else {
      pt[b * NSEQ + 8 * g + (tid - 8)] = s;
    }
  }
}

// ---------- kernel B: serial dynamics; 512 threads, 4 contiguous elems/thread ----------
__global__ __launch_bounds__(NT) void kB(const float* __restrict__ rho_us,
                                         const float* __restrict__ pt,
                                         const float* __restrict__ phi,
                                         float* __restrict__ rho_f) {
  __shared__ float cb[NSEQ];                    // conv staging (single buffer)
  __shared__ float up0M[NSEQ];                  // up0 = leray(grad1 v), cached in LDS
  __shared__ float vE0[NT];
  __shared__ float rhoE0[NT], rhoE3[NT];
  __shared__ float upE3[NT];
  __shared__ float yE0[3][NT], yE3[3][NT];
  __shared__ float4 pairE[2][NT];               // (sgw0,sg0,sgw3,sg3), by h-parity
  __shared__ float red[256];
  __shared__ float red2[8];

  const int tid = threadIdx.x;
  const int b = blockIdx.x;
  const int tm1 = (tid - 1) & (NT - 1);
  const int tp1 = (tid + 1) & (NT - 1);
  int gen = 0;
  const float CFL_ = 0.4f;

  float4 phv = *(const float4*)(phi + 4 * tid);
  float phir[4] = {phv.x, phv.y, phv.z, phv.w};

  // ---- v = normalize(|dwt1d(per_token)| * sqrt(D)) ----
  float v_r[4];
  {
    const float* ptb = pt + b * NSEQ;
    float vl[4]; float part = 0.f;
#pragma unroll
    for (int j = 0; j < 4; ++j) {
      float c;
      if (tid < 64) {
        int r = (4 * tid + j) * 8;
        float t01 = ptb[r] + ptb[r+1], t23 = ptb[r+2] + ptb[r+3];
        float t45 = ptb[r+4] + ptb[r+5], t67 = ptb[r+6] + ptb[r+7];
        c = ((t01 + t23) + (t45 + t67)) * INV2R2;
      } else if (tid < 128) {
        int r = (4 * (tid - 64) + j) * 8;
        float t01 = ptb[r] + ptb[r+1], t23 = ptb[r+2] + ptb[r+3];
        float t45 = ptb[r+4] + ptb[r+5], t67 = ptb[r+6] + ptb[r+7];
        c = ((t01 + t23) - (t45 + t67)) * INV2R2;
      } else if (tid < 256) {
        int r = (4 * (tid - 128) + j) * 4;
        c = ((ptb[r] + ptb[r+1]) - (ptb[r+2] + ptb[r+3])) * 0.5f;
      } else {
        int r = (4 * (tid - 256) + j) * 2;
        c = (ptb[r] - ptb[r+1]) * INVR2;
      }
      float val = sqrtf(2048.0f * c * c) + EPSF;
      vl[j] = val; part += val;
    }
    float sv = block_sum(part, red, tid, gen);
    float inv = 1.0f / sv;
#pragma unroll
    for (int j = 0; j < 4; ++j) v_r[j] = vl[j] * inv;
    vE0[tid] = v_r[0];
  }
  // ---- rho = normalize(rho_us) ----
  float rho_r[4];
  {
    float4 rv = *(const float4*)(rho_us + b * NSEQ + 4 * tid);
    float rl[4] = {rv.x + EPSF, rv.y + EPSF, rv.z + EPSF, rv.w + EPSF};
    float part = rl[0] + rl[1] + rl[2] + rl[3];
    float sr = block_sum(part, red, tid, gen);   // barrier publishes vE0
    float inv = 1.f / sr;
#pragma unroll
    for (int j = 0; j < 4; ++j) rho_r[j] = rl[j] * inv;
  }

  // ---- up0 = leray(grad1(v)) : computed ONCE, cached in LDS for every outer k ----
  float up_r[4];
  float mx, mx0, um1c;
  {
    float vp4c = vE0[tp1];
    float u0[4] = {v_r[1] - v_r[0], v_r[2] - v_r[1], v_r[3] - v_r[2], vp4c - v_r[3]};
    conv65(u0, up_r, cb, tid);
    *(float4*)(up0M + (tid << 2)) = make_float4(up_r[0], up_r[1], up_r[2], up_r[3]);
    float mm = fmaxf(fmaxf(fabsf(up_r[0]), fabsf(up_r[1])),
                     fmaxf(fabsf(up_r[2]), fabsf(up_r[3])));
    mm = wave_max(mm);
    if ((tid & 63) == 0) red2[tid >> 6] = mm;
    __syncthreads();
    float4 r2a = *(float4*)(red2), r2b = *(float4*)(red2 + 4);
    mx = rfl(fmaxf(fmaxf(fmaxf(r2a.x, r2a.y), fmaxf(r2a.z, r2a.w)),
                   fmaxf(fmaxf(r2b.x, r2b.y), fmaxf(r2b.z, r2b.w))));
    um1c = up0M[(4 * tid - 1) & (NSEQ - 1)];
    mx0 = mx;
  }

  for (int k = 0; k < 3; ++k) {
    // ---- reaction ----
    {
      float tl[4]; float part = 0.f;
#pragma unroll
      for (int j = 0; j < 4; ++j) {
        float r = rho_r[j];
        float t = r * expf(-0.1f * (phir[j] + logf(r)));
        float t2 = fabsf(t) + EPSF;
        tl[j] = t2; part += t2;
      }
      float s = block_sum(part, red, tid, gen);
      float inv = 1.f / s;
#pragma unroll
      for (int j = 0; j < 4; ++j) rho_r[j] = tl[j] * inv;
      rhoE0[tid] = rho_r[0]; rhoE3[tid] = rho_r[3];
    }
    __syncthreads();                       // publish rhoE
    const float rhom1 = rhoE3[tm1], rhop4 = rhoE0[tp1];  // constant over the 5 steps
    if (k > 0) {                           // u = grad1(v) identical every k -> reuse up0
      float4 u4 = *(const float4*)(up0M + (tid << 2));
      up_r[0] = u4.x; up_r[1] = u4.y; up_r[2] = u4.z; up_r[3] = u4.w;
      um1c = up0M[(4 * tid - 1) & (NSEQ - 1)];
      mx = mx0;
    }

    float y_r[4][4];
    for (int step = 0; step < 5; ++step) {
      float dt = CFL_ / (mx + EPSF);
      // ---- forward rollout (ntie in h=0, cost-dot in h=3, passA(3) mirrored) ----
      float sarr[4]; float spv = 1.f; float ntie = 1.f, dot = 0.f;
#pragma unroll
      for (int h = 0; h < 4; ++h) {
        float invp = 1.f / spv;
        float rr[6];
        if (h == 0) {
          rr[0] = rhom1; rr[1] = rho_r[0]; rr[2] = rho_r[1];
          rr[3] = rho_r[2]; rr[4] = rho_r[3]; rr[5] = rhop4;
        } else {
          rr[0] = (fabsf(yE3[h-1][tm1]) + EPSF) * invp;
#pragma unroll
          for (int j = 0; j < 4; ++j) rr[j+1] = (fabsf(y_r[h-1][j]) + EPSF) * invp;
          rr[5] = (fabsf(yE0[h-1][tp1]) + EPSF) * invp;
        }
        float part2 = 0.f, aux = 0.f;
#pragma unroll
        for (int j = 0; j < 4; ++j) {
          float ri = rr[j+1], rim1 = rr[j], rip1 = rr[j+2];
          float ui = up_r[j], um = j ? up_r[j-1] : um1c;
          float Fi = ui > 0.f ? ui * ri : ui * rip1;
          float Fm = um > 0.f ? um * rim1 : um * ri;
          float yv = ri - dt * (Fi - Fm);
          y_r[h][j] = yv;
          float ayv = fabsf(yv) + EPSF;
          part2 += ayv;
          if (h == 0) aux += (fabsf(ui) == mx) ? 1.f : 0.f;
          if (h == 3) aux += (1.f - v_r[j]) * 0.125f * ayv;
        }
        if (h < 3) { yE0[h][tid] = y_r[h][0]; yE3[h][tid] = y_r[h][3]; }
        if (h == 3) {
          float sg0 = sgnf(y_r[3][0]), sg3 = sgnf(y_r[3][3]);
          pairE[1][tid] = make_float4(sg0 * (1.f - v_r[0]) * 0.125f, sg0,
                                      sg3 * (1.f - v_r[3]) * 0.125f, sg3);
        }
        if (h == 0) { float o1, o2; block_sum2(part2, aux, red, tid, gen, o1, o2); sarr[0] = o1; ntie = o2; }
        else if (h == 3) { float o1, o2; block_sum2(part2, aux, red, tid, gen, o1, o2); sarr[3] = o1; dot = o2 / o1; }
        else sarr[h] = block_sum(part2, red, tid, gen);
        spv = sarr[h];
      }
      // ---- backward (passA folded into dot barriers via pairE mirrors) ----
      float wreg[4], upbar[4];
#pragma unroll
      for (int j = 0; j < 4; ++j) { wreg[j] = (1.f - v_r[j]) * 0.125f; upbar[j] = 0.f; }
      float dtb_part = 0.f;
#pragma unroll
      for (int h = 3; h >= 0; --h) {
        float invst = 1.f / sarr[h];
        float invp = (h > 0) ? 1.f / sarr[h-1] : 0.f;
        const int bo = h & 1;
        float yb_r[4];
#pragma unroll
        for (int j = 0; j < 4; ++j)
          yb_r[j] = sgnf(y_r[h][j]) * (wreg[j] - dot) * invst;
        float4 pm = pairE[bo][tm1], pp = pairE[bo][tp1];
        float ybm1 = (pm.z - dot * pm.w) * invst;
        float ybp4 = (pp.x - dot * pp.y) * invst;
        float rr[6];
        if (h == 0) {
          rr[0] = rhom1; rr[1] = rho_r[0]; rr[2] = rho_r[1];
          rr[3] = rho_r[2]; rr[4] = rho_r[3]; rr[5] = rhop4;
        } else {
          rr[0] = (fabsf(yE3[h-1][tm1]) + EPSF) * invp;
#pragma unroll
          for (int j = 0; j < 4; ++j) rr[j+1] = (fabsf(y_r[h-1][j]) + EPSF) * invp;
          rr[5] = (fabsf(yE0[h-1][tp1]) + EPSF) * invp;
        }
        float dotn = 0.f;
#pragma unroll
        for (int j = 0; j < 4; ++j) {
          float ri = rr[j+1], rim1 = rr[j], rip1 = rr[j+2];
          float ui = up_r[j], um = j ? up_r[j-1] : um1c;
          float ybi = yb_r[j];
          float ybm = j ? yb_r[j-1] : ybm1;
          float ybp = (j < 3) ? yb_r[j+1] : ybp4;
          float Fbi = dt * (ybp - ybi);
          float Fbm = dt * (ybi - ybm);
          float wn = ybi;
          if (ui > 0.f)    wn += Fbi * ui;
          if (!(um > 0.f)) wn += Fbm * um;
          upbar[j] += Fbi * (ui > 0.f ? ri : rip1);
          float Fi = ui > 0.f ? ui * ri : ui * rip1;
          float Fm = um > 0.f ? um * rim1 : um * ri;
          dtb_part -= ybi * (Fi - Fm);
          if (h > 0) dotn += wn * ri;
          wreg[j] = wn;
        }
        if (h > 0) {
          float sgA = sgnf(y_r[h-1][0]), sgB = sgnf(y_r[h-1][3]);
          pairE[(h - 1) & 1][tid] = make_float4(sgA * wreg[0], sgA, sgB * wreg[3], sgB);
          dot = block_sum(dotn, red, tid, gen);
        }
      }
      float dtbar = block_sum(dtb_part, red, tid, gen);
      float md = mx + EPSF;
      float mbar = dtbar * (-CFL_ / (md * md));
      float tiesc = mbar / ntie;
#pragma unroll
      for (int j = 0; j < 4; ++j) {
        float ui = up_r[j];
        if (fabsf(ui) == mx) upbar[j] += tiesc * sgnf(ui);
      }
      // ---- up -= 0.1 * conv(LK^2, upbar); epilogue folds max + edge publish ----
      float accv[4];
      conv129(upbar, accv, cb, tid);
#pragma unroll
      for (int j = 0; j < 4; ++j) up_r[j] -= 0.1f * accv[j];
      upE3[tid] = up_r[3];
      {
        float mm = fmaxf(fmaxf(fabsf(up_r[0]), fabsf(up_r[1])),
                         fmaxf(fabsf(up_r[2]), fabsf(up_r[3])));
        mm = wave_max(mm);
        if ((tid & 63) == 0) red2[tid >> 6] = mm;
      }
      __syncthreads();
      float4 r2a = *(float4*)(red2), r2b = *(float4*)(red2 + 4);
      mx = rfl(fmaxf(fmaxf(fmaxf(r2a.x, r2a.y), fmaxf(r2a.z, r2a.w)),
                     fmaxf(fmaxf(r2b.x, r2b.y), fmaxf(r2b.z, r2b.w))));
      um1c = upE3[tm1];
    }
    // ---- outer: up already = leray(u_final); advect + normalize ----
    float dt = CFL_ / (mx + EPSF);
    float kap = (k == 0) ? 0.01f : ((k == 1) ? 0.005f : 0.0f);
    float rr[6];
    rr[0] = rhom1; rr[1] = rho_r[0]; rr[2] = rho_r[1];
    rr[3] = rho_r[2]; rr[4] = rho_r[3]; rr[5] = rhop4;
    float ylc[4]; float p2 = 0.f;
#pragma unroll
    for (int j = 0; j < 4; ++j) {
      float ri = rr[j+1], rim1 = rr[j], rip1 = rr[j+2];
      float ui = up_r[j], um = j ? up_r[j-1] : um1c;
      float Fi = ui > 0.f ? ui * ri : ui * rip1;
      float Fm = um > 0.f ? um * rim1 : um * ri;
      float yv = ri - dt * (Fi - Fm) + kap * dt * (rip1 + rim1 - 2.f * ri);
      ylc[j] = yv; p2 += fabsf(yv) + EPSF;
    }
    float s = block_sum(p2, red, tid, gen);
    float inv = 1.f / s;
#pragma unroll
    for (int j = 0; j < 4; ++j) rho_r[j] = (fabsf(ylc[j]) + EPSF) * inv;
  }
  // ---- final: rho_f = (rho + 0.1 v)/sum ----
  {
    float fl[4]; float part = 0.f;
#pragma unroll
    for (int j = 0; j < 4; ++j) {
      float f = rho_r[j] + 0.1f * v_r[j];
      fl[j] = f; part += f;
    }
    float s = block_sum(part, red, tid, gen);
    float inv = 1.f / s;
    *(float4*)(rho_f + b * NSEQ + 4 * tid) =
        make_float4(fl[0] * inv, fl[1] * inv, fl[2] * inv, fl[3] * inv);
  }
}

// ---------- kernel C: out = IDWT3(rho_f[:,:,None] * band_w[BAND_IDX]) ----------
__global__ __launch_bounds__(256) void kC(const float* __restrict__ rho_f,
                                          const float* __restrict__ bw,
                                          float* __restrict__ out) {
  const int blk = blockIdx.x;
  const int b = blk >> 8;
  const int g = blk & 255;
  __shared__ float q[8];
  if (threadIdx.x < 8) {
    int t = threadIdx.x;
    const float* rb = rho_f + b * NSEQ;
    float val;
    if (t == 0)      val = rb[g] * INV2R2;
    else if (t == 1) val = rb[256 + g] * INV2R2;
    else if (t < 4)  val = rb[512 + 2 * g + (t - 2)] * 0.5f;
    else             val = rb[1024 + 4 * g + (t - 4)] * INVR2;
    q[t] = val;
  }
  __syncthreads();
  float* ob = out + (((size_t)b * NSEQ) + (size_t)g * 8) * 2048;
  for (int c = threadIdx.x * 4; c < 2048; c += 1024) {
    float4 B0 = *(const float4*)(bw + c);
    float4 B1 = *(const float4*)(bw + 2048 + c);
    float4 B2 = *(const float4*)(bw + 4096 + c);
    float4 B3 = *(const float4*)(bw + 6144 + c);
    float b0[4] = {B0.x, B0.y, B0.z, B0.w};
    float b1[4] = {B1.x, B1.y, B1.z, B1.w};
    float b2[4] = {B2.x, B2.y, B2.z, B2.w};
    float b3[4] = {B3.x, B3.y, B3.z, B3.w};
    float o[8][4];
#pragma unroll
    for (int cc = 0; cc < 4; ++cc) {
      float pa = q[0] * b0[cc], pd3 = q[1] * b1[cc];
      float p2a = q[2] * b2[cc], p2b = q[3] * b2[cc];
      float e0 = pa + pd3, e1 = pa - pd3;
      float f0 = e0 + p2a, f1 = e0 - p2a, f2 = e1 + p2b, f3 = e1 - p2b;
      float g0 = q[4] * b3[cc], g1 = q[5] * b3[cc], g2 = q[6] * b3[cc], g3 = q[7] * b3[cc];
      o[0][cc] = f0 + g0; o[1][cc] = f0 - g0;
      o[2][cc] = f1 + g1; o[3][cc] = f1 - g1;
      o[4][cc] = f2 + g2; o[5][cc] = f2 - g2;
      o[6][cc] = f3 + g3; o[7][cc] = f3 - g3;
    }
#pragma unroll
    for (int j = 0; j < 8; ++j) {
      float4 t = make_float4(o[j][0], o[j][1], o[j][2], o[j][3]);
      *(float4*)(ob + (size_t)j * 2048 + c) = t;
    }
  }
}

extern "C" void kernel_launch(void* const* d_in, const int* in_sizes, int n_in,
                              void* d_out, int out_size, void* d_ws, size_t ws_size,
                              hipStream_t stream) {
  (void)in_sizes; (void)n_in; (void)out_size; (void)ws_size;
  const float* x   = (const float*)d_in[0];
  const float* wv  = (const float*)d_in[1];
  const float* phi = (const float*)d_in[2];
  const float* bw  = (const float*)d_in[3];
  float* out = (float*)d_out;
  float* rho_us = (float*)d_ws;
  float* pt     = rho_us + 8 * NSEQ;
  float* rho_f  = pt + 8 * NSEQ;

  kA<<<dim3(2048), dim3(256), 0, stream>>>(x, wv, rho_us, pt);
  kB<<<dim3(8), dim3(NT), 0, stream>>>(rho_us, pt, phi, rho_f);
  kC<<<dim3(2048), dim3(256), 0, stream>>>(rho_f, bw, out);
}

// Round 13
// 166.393 us; speedup vs baseline: 1.1811x; 1.0791x over previous
//
#include <hip/hip_runtime.h>
#include <math.h>

#define NSEQ 2048
#define EPSF 1e-8f
#define INV2R2 0.35355339059327373f
#define INVR2  0.7071067811865476f
#define NT 512   // HW law (r2/r5/r8/r9/r11): VGPR cap = 65536/B. 512 threads -> 128 regs.

// ---------- compile-time Leray conv taps ----------
// K = -0.5*sum M^i (50 Jacobi iters), LK = delta - 2nd-diff(K) (support |o|<=50).
// lk65: LK truncated to radius 32 (tail ~3e-7, validated r5/r6).
// lk2:  (LK*LK) truncated to radius 48 — exact double conv of untruncated LK,
//       tail-L1 beyond 48 ~1e-7 (pairs need both factors' indices >=16: 
//       LK(16)~1e-3, LK(24)~8e-5, LK(32)~1.3e-6 -> LK2(48)~3e-8). Per-conv
//       output error ~1e-9 abs, 3 orders below the validated lk65 truncation.
struct TapsAll { float lk65[65]; float lk2[97]; };

constexpr TapsAll make_taps() {
  TapsAll t{};
  double K[99] = {};
  for (int j = -49; j <= 49; ++j) {
    int aj = j < 0 ? -j : j;
    double term = 1.0;
    for (int q = 0; q < aj; ++q) term *= 0.5;
    double sum = term;
    for (int i = aj + 2; i <= 49; i += 2) {
      int m = (i + j) / 2;
      term *= (double)((i - 1) * i) / (4.0 * (double)m * (double)(i - m));
      sum += term;
    }
    K[j + 49] = -0.5 * sum;
  }
  double LKd[101] = {};
  for (int o = -50; o <= 50; ++o) {
    double km1 = (o - 1 >= -49 && o - 1 <= 49) ? K[o - 1 + 49] : 0.0;
    double k0  = (o     >= -49 && o     <= 49) ? K[o + 49]     : 0.0;
    double kp1 = (o + 1 >= -49 && o + 1 <= 49) ? K[o + 1 + 49] : 0.0;
    LKd[o + 50] = ((o == 0) ? 1.0 : 0.0) - (kp1 - 2.0 * k0 + km1);
  }
  for (int o = -32; o <= 32; ++o) t.lk65[o + 32] = (float)LKd[o + 50];
  for (int o = -48; o <= 48; ++o) {
    double s = 0.0;
    int alo = (o - 50 > -50) ? o - 50 : -50;
    int ahi = (o + 50 <  50) ? o + 50 :  50;
    for (int a = alo; a <= ahi; ++a) s += LKd[a + 50] * LKd[o - a + 50];
    t.lk2[o + 48] = (float)s;
  }
  return t;
}
constexpr TapsAll TAPS = make_taps();

// ---------- uniform-scalar pin: value identical across lanes -> SGPR ----------
__device__ __forceinline__ float rfl(float x) {
  return __int_as_float(__builtin_amdgcn_readfirstlane(__float_as_int(x)));
}

// ---------- reduction helpers (512 threads = 8 waves) ----------
__device__ __forceinline__ float wave_sum(float x) {
#pragma unroll
  for (int m = 1; m < 64; m <<= 1) x += __shfl_xor(x, m, 64);
  return x;
}
__device__ __forceinline__ float wave_max(float x) {
#pragma unroll
  for (int m = 1; m < 64; m <<= 1) x = fmaxf(x, __shfl_xor(x, m, 64));
  return x;
}
__device__ __forceinline__ float block_sum(float x, float* red, int tid, int& gen) {
  float w = wave_sum(x);
  int slot = (gen & 7) << 5; gen++;
  if ((tid & 63) == 0) red[slot + (tid >> 6)] = w;
  __syncthreads();
  float4 a = *(float4*)(red + slot), b = *(float4*)(red + slot + 4);
  return rfl(((a.x + a.y) + (a.z + a.w)) + ((b.x + b.y) + (b.z + b.w)));
}
__device__ __forceinline__ void block_sum2(float a, float b, float* red, int tid, int& gen,
                                           float& oa, float& ob) {
  float wa = wave_sum(a), wb = wave_sum(b);
  int slot = (gen & 7) << 5; gen++;
  if ((tid & 63) == 0) { int w = tid >> 6; red[slot + w] = wa; red[slot + 16 + w] = wb; }
  __syncthreads();
  float4 a0 = *(float4*)(red + slot),      a1 = *(float4*)(red + slot + 4);
  float4 b0 = *(float4*)(red + slot + 16), b1 = *(float4*)(red + slot + 20);
  oa = rfl(((a0.x + a0.y) + (a0.z + a0.w)) + ((a1.x + a1.y) + (a1.z + a1.w)));
  ob = rfl(((b0.x + b0.y) + (b0.z + b0.w)) + ((b1.x + b1.y) + (b1.z + b1.w)));
}
__device__ __forceinline__ float sgnf(float x) {
  return (x > 0.f) ? 1.f : ((x < 0.f) ? -1.f : 0.f);
}

// ---------- 65-tap conv (radius 32): regs in, regs out, single cb buffer ----------
__device__ __forceinline__ void conv65(const float in[4], float acc[4],
                                       float* __restrict__ cb, int tid) {
  *(float4*)(cb + (tid << 2)) = make_float4(in[0], in[1], in[2], in[3]);
  __syncthreads();
  const int base = tid << 2;
  acc[0] = 0.f; acc[1] = 0.f; acc[2] = 0.f; acc[3] = 0.f;
#pragma unroll
  for (int m = 0; m < 17; ++m) {
    const int idx = (base - 32 + 4 * m) & (NSEQ - 1);
    const float4 c4 = *(const float4*)(cb + idx);
    const float cv[4] = {c4.x, c4.y, c4.z, c4.w};
#pragma unroll
    for (int jj = 0; jj < 4; ++jj) {
      const int d = 4 * m + jj;
#pragma unroll
      for (int j = 0; j < 4; ++j) {
        const int o = d - 32 - j;
        if (o >= -32 && o <= 32) acc[j] = fmaf(TAPS.lk65[o + 32], cv[jj], acc[j]);
      }
    }
  }
}

// ---------- 97-tap conv (radius 48, LK^2): one per MPC step ----------
__device__ __forceinline__ void conv97(const float in[4], float acc[4],
                                       float* __restrict__ cb, int tid) {
  *(float4*)(cb + (tid << 2)) = make_float4(in[0], in[1], in[2], in[3]);
  __syncthreads();
  const int base = tid << 2;
  acc[0] = 0.f; acc[1] = 0.f; acc[2] = 0.f; acc[3] = 0.f;
#pragma unroll
  for (int m = 0; m < 25; ++m) {
    const int idx = (base - 48 + 4 * m) & (NSEQ - 1);
    const float4 c4 = *(const float4*)(cb + idx);
    const float cv[4] = {c4.x, c4.y, c4.z, c4.w};
#pragma unroll
    for (int jj = 0; jj < 4; ++jj) {
      const int d = 4 * m + jj;
#pragma unroll
      for (int j = 0; j < 4; ++j) {
        const int o = d - 48 - j;
        if (o >= -48 && o <= 48) acc[j] = fmaf(TAPS.lk2[o + 48], cv[jj], acc[j]);
      }
    }
  }
}

// ---------- kernel A: rho_unscaled (L2 of DWT rows) + per_token ----------
__global__ __launch_bounds__(256) void kA(const float* __restrict__ x,
                                          const float* __restrict__ wv,
                                          float* __restrict__ rho_us,
                                          float* __restrict__ pt) {
  const int blk = blockIdx.x;
  const int b = blk >> 8;
  const int g = blk & 255;
  const float* xb = x + (((size_t)b * NSEQ) + (size_t)g * 8) * 2048;
  const int tid = threadIdx.x;
  float sq[8] = {0.f, 0.f, 0.f, 0.f, 0.f, 0.f, 0.f, 0.f};
  float pp[8] = {0.f, 0.f, 0.f, 0.f, 0.f, 0.f, 0.f, 0.f};
  for (int c = tid * 4; c < 2048; c += 1024) {
    float4 w4 = *(const float4*)(wv + c);
    float wj[4] = {w4.x, w4.y, w4.z, w4.w};
    float xv[8][4];
#pragma unroll
    for (int r = 0; r < 8; ++r) {
      float4 t = *(const float4*)(xb + (size_t)r * 2048 + c);
      xv[r][0] = t.x; xv[r][1] = t.y; xv[r][2] = t.z; xv[r][3] = t.w;
    }
#pragma unroll
    for (int j = 0; j < 4; ++j) {
      float x0 = xv[0][j], x1 = xv[1][j], x2 = xv[2][j], x3 = xv[3][j];
      float x4 = xv[4][j], x5 = xv[5][j], x6 = xv[6][j], x7 = xv[7][j];
      float t01 = x0 + x1, t23 = x2 + x3, t45 = x4 + x5, t67 = x6 + x7;
      float a = t01 + t23, bb = t45 + t67;
      float c3 = a + bb, d3 = a - bb, d2a = t01 - t23, d2b = t45 - t67;
      float d10 = x0 - x1, d11 = x2 - x3, d12 = x4 - x5, d13 = x6 - x7;
      sq[0] += c3 * c3;  sq[1] += d3 * d3;  sq[2] += d2a * d2a; sq[3] += d2b * d2b;
      sq[4] += d10 * d10; sq[5] += d11 * d11; sq[6] += d12 * d12; sq[7] += d13 * d13;
      float w = wj[j];
      pp[0] += x0 * w; pp[1] += x1 * w; pp[2] += x2 * w; pp[3] += x3 * w;
      pp[4] += x4 * w; pp[5] += x5 * w; pp[6] += x6 * w; pp[7] += x7 * w;
    }
  }
  __shared__ float sred[4][16];
  float vals[16];
#pragma unroll
  for (int q = 0; q < 8; ++q) vals[q] = sq[q];
#pragma unroll
  for (int q = 0; q < 8; ++q) vals[8 + q] = pp[q];
#pragma unroll
  for (int q = 0; q < 16; ++q) vals[q] = wave_sum(vals[q]);
  int lane = tid & 63, wid = tid >> 6;
  if (lane == 0) {
#pragma unroll
    for (int q = 0; q < 16; ++q) sred[wid][q] = vals[q];
  }
  __syncthreads();
  if (tid < 16) {
    float s = sred[0][tid] + sred[1][tid] + sred[2][tid] + sred[3][tid];
    if (tid < 8) {
      float scale = (tid < 2) ? 0.125f : ((tid < 4) ? 0.25f : 0.5f);
      int pos = (tid == 0) ? g : (tid == 1) ? (256 + g)
               : (tid < 4) ? (512 + 2 * g + (tid - 2)) : (1024 + 4 * g + (tid - 4));
      rho_us[b * NSEQ + pos] = sqrtf(s * scale);
    } else {
      pt[b * NSEQ + 8 * g + (tid - 8)] = s;
    }
  }
}

// ---------- kernel B: serial dynamics; 512 threads, 4 contiguous elems/thread ----------
__global__ __launch_bounds__(NT) void kB(const float* __restrict__ rho_us,
                                         const float* __restrict__ pt,
                                         const float* __restrict__ phi,
                                         float* __restrict__ rho_f) {
  __shared__ float cb[NSEQ];                    // conv staging (single buffer)
  __shared__ float up0M[NSEQ];                  // up0 = leray(grad1 v), cached in LDS
  __shared__ float vE0[NT];
  __shared__ float rhoE0[NT], rhoE3[NT];
  __shared__ float upE3[NT];
  __shared__ float yE0[3][NT], yE3[3][NT];
  __shared__ float4 pairE[2][NT];               // (sgw0,sg0,sgw3,sg3), by h-parity
  __shared__ float red[256];
  __shared__ float red2[8];

  const int tid = threadIdx.x;
  const int b = blockIdx.x;
  const int tm1 = (tid - 1) & (NT - 1);
  const int tp1 = (tid + 1) & (NT - 1);
  int gen = 0;
  const float CFL_ = 0.4f;

  // reaction only ever needs exp(-0.1*phi): hoist it (register-neutral vs phi).
  float4 phv = *(const float4*)(phi + 4 * tid);
  float ephi[4] = {__expf(-0.1f * phv.x), __expf(-0.1f * phv.y),
                   __expf(-0.1f * phv.z), __expf(-0.1f * phv.w)};

  // ---- v = normalize(|dwt1d(per_token)| * sqrt(D)) ----
  float v_r[4];
  {
    const float* ptb = pt + b * NSEQ;
    float vl[4]; float part = 0.f;
#pragma unroll
    for (int j = 0; j < 4; ++j) {
      float c;
      if (tid < 64) {
        int r = (4 * tid + j) * 8;
        float t01 = ptb[r] + ptb[r+1], t23 = ptb[r+2] + ptb[r+3];
        float t45 = ptb[r+4] + ptb[r+5], t67 = ptb[r+6] + ptb[r+7];
        c = ((t01 + t23) + (t45 + t67)) * INV2R2;
      } else if (tid < 128) {
        int r = (4 * (tid - 64) + j) * 8;
        float t01 = ptb[r] + ptb[r+1], t23 = ptb[r+2] + ptb[r+3];
        float t45 = ptb[r+4] + ptb[r+5], t67 = ptb[r+6] + ptb[r+7];
        c = ((t01 + t23) - (t45 + t67)) * INV2R2;
      } else if (tid < 256) {
        int r = (4 * (tid - 128) + j) * 4;
        c = ((ptb[r] + ptb[r+1]) - (ptb[r+2] + ptb[r+3])) * 0.5f;
      } else {
        int r = (4 * (tid - 256) + j) * 2;
        c = (ptb[r] - ptb[r+1]) * INVR2;
      }
      float val = sqrtf(2048.0f * c * c) + EPSF;
      vl[j] = val; part += val;
    }
    float sv = block_sum(part, red, tid, gen);
    float inv = 1.0f / sv;
#pragma unroll
    for (int j = 0; j < 4; ++j) v_r[j] = vl[j] * inv;
    vE0[tid] = v_r[0];
  }
  // ---- rho = normalize(rho_us) ----
  float rho_r[4];
  {
    float4 rv = *(const float4*)(rho_us + b * NSEQ + 4 * tid);
    float rl[4] = {rv.x + EPSF, rv.y + EPSF, rv.z + EPSF, rv.w + EPSF};
    float part = rl[0] + rl[1] + rl[2] + rl[3];
    float sr = block_sum(part, red, tid, gen);   // barrier publishes vE0
    float inv = 1.f / sr;
#pragma unroll
    for (int j = 0; j < 4; ++j) rho_r[j] = rl[j] * inv;
  }

  // ---- up0 = leray(grad1(v)) : computed ONCE, cached in LDS for every outer k ----
  float up_r[4];
  float mx, mx0, um1c;
  {
    float vp4c = vE0[tp1];
    float u0[4] = {v_r[1] - v_r[0], v_r[2] - v_r[1], v_r[3] - v_r[2], vp4c - v_r[3]};
    conv65(u0, up_r, cb, tid);
    *(float4*)(up0M + (tid << 2)) = make_float4(up_r[0], up_r[1], up_r[2], up_r[3]);
    float mm = fmaxf(fmaxf(fabsf(up_r[0]), fabsf(up_r[1])),
                     fmaxf(fabsf(up_r[2]), fabsf(up_r[3])));
    mm = wave_max(mm);
    if ((tid & 63) == 0) red2[tid >> 6] = mm;
    __syncthreads();
    float4 r2a = *(float4*)(red2), r2b = *(float4*)(red2 + 4);
    mx = rfl(fmaxf(fmaxf(fmaxf(r2a.x, r2a.y), fmaxf(r2a.z, r2a.w)),
                   fmaxf(fmaxf(r2b.x, r2b.y), fmaxf(r2b.z, r2b.w))));
    um1c = up0M[(4 * tid - 1) & (NSEQ - 1)];
    mx0 = mx;
  }

  for (int k = 0; k < 3; ++k) {
    // ---- reaction: rho <- normalize(|rho^{0.9-ish} * ephi|) via fast exp/log ----
    {
      float tl[4]; float part = 0.f;
#pragma unroll
      for (int j = 0; j < 4; ++j) {
        float r = rho_r[j];
        float t = r * ephi[j] * __expf(-0.1f * __logf(r));
        float t2 = fabsf(t) + EPSF;
        tl[j] = t2; part += t2;
      }
      float s = block_sum(part, red, tid, gen);
      float inv = 1.f / s;
#pragma unroll
      for (int j = 0; j < 4; ++j) rho_r[j] = tl[j] * inv;
      rhoE0[tid] = rho_r[0]; rhoE3[tid] = rho_r[3];
    }
    __syncthreads();                       // publish rhoE
    const float rhom1 = rhoE3[tm1], rhop4 = rhoE0[tp1];  // constant over the 5 steps
    if (k > 0) {                           // u = grad1(v) identical every k -> reuse up0
      float4 u4 = *(const float4*)(up0M + (tid << 2));
      up_r[0] = u4.x; up_r[1] = u4.y; up_r[2] = u4.z; up_r[3] = u4.w;
      um1c = up0M[(4 * tid - 1) & (NSEQ - 1)];
      mx = mx0;
    }

    float y_r[4][4];
    for (int step = 0; step < 5; ++step) {
      float dt = CFL_ / (mx + EPSF);
      // ---- forward rollout (ntie in h=0, cost-dot in h=3, passA(3) mirrored) ----
      float sarr[4]; float spv = 1.f; float ntie = 1.f, dot = 0.f;
#pragma unroll
      for (int h = 0; h < 4; ++h) {
        float invp = 1.f / spv;
        float rr[6];
        if (h == 0) {
          rr[0] = rhom1; rr[1] = rho_r[0]; rr[2] = rho_r[1];
          rr[3] = rho_r[2]; rr[4] = rho_r[3]; rr[5] = rhop4;
        } else {
          rr[0] = (fabsf(yE3[h-1][tm1]) + EPSF) * invp;
#pragma unroll
          for (int j = 0; j < 4; ++j) rr[j+1] = (fabsf(y_r[h-1][j]) + EPSF) * invp;
          rr[5] = (fabsf(yE0[h-1][tp1]) + EPSF) * invp;
        }
        float part2 = 0.f, aux = 0.f;
#pragma unroll
        for (int j = 0; j < 4; ++j) {
          float ri = rr[j+1], rim1 = rr[j], rip1 = rr[j+2];
          float ui = up_r[j], um = j ? up_r[j-1] : um1c;
          float Fi = ui > 0.f ? ui * ri : ui * rip1;
          float Fm = um > 0.f ? um * rim1 : um * ri;
          float yv = ri - dt * (Fi - Fm);
          y_r[h][j] = yv;
          float ayv = fabsf(yv) + EPSF;
          part2 += ayv;
          if (h == 0) aux += (fabsf(ui) == mx) ? 1.f : 0.f;
          if (h == 3) aux += (1.f - v_r[j]) * 0.125f * ayv;
        }
        if (h < 3) { yE0[h][tid] = y_r[h][0]; yE3[h][tid] = y_r[h][3]; }
        if (h == 3) {
          float sg0 = sgnf(y_r[3][0]), sg3 = sgnf(y_r[3][3]);
          pairE[1][tid] = make_float4(sg0 * (1.f - v_r[0]) * 0.125f, sg0,
                                      sg3 * (1.f - v_r[3]) * 0.125f, sg3);
        }
        if (h == 0) { float o1, o2; block_sum2(part2, aux, red, tid, gen, o1, o2); sarr[0] = o1; ntie = o2; }
        else if (h == 3) { float o1, o2; block_sum2(part2, aux, red, tid, gen, o1, o2); sarr[3] = o1; dot = o2 / o1; }
        else sarr[h] = block_sum(part2, red, tid, gen);
        spv = sarr[h];
      }
      // ---- backward (passA folded into dot barriers via pairE mirrors) ----
      float wreg[4], upbar[4];
#pragma unroll
      for (int j = 0; j < 4; ++j) { wreg[j] = (1.f - v_r[j]) * 0.125f; upbar[j] = 0.f; }
      float dtb_part = 0.f;
#pragma unroll
      for (int h = 3; h >= 0; --h) {
        float invst = 1.f / sarr[h];
        float invp = (h > 0) ? 1.f / sarr[h-1] : 0.f;
        const int bo = h & 1;
        float yb_r[4];
#pragma unroll
        for (int j = 0; j < 4; ++j)
          yb_r[j] = sgnf(y_r[h][j]) * (wreg[j] - dot) * invst;
        float4 pm = pairE[bo][tm1], pp = pairE[bo][tp1];
        float ybm1 = (pm.z - dot * pm.w) * invst;
        float ybp4 = (pp.x - dot * pp.y) * invst;
        float rr[6];
        if (h == 0) {
          rr[0] = rhom1; rr[1] = rho_r[0]; rr[2] = rho_r[1];
          rr[3] = rho_r[2]; rr[4] = rho_r[3]; rr[5] = rhop4;
        } else {
          rr[0] = (fabsf(yE3[h-1][tm1]) + EPSF) * invp;
#pragma unroll
          for (int j = 0; j < 4; ++j) rr[j+1] = (fabsf(y_r[h-1][j]) + EPSF) * invp;
          rr[5] = (fabsf(yE0[h-1][tp1]) + EPSF) * invp;
        }
        float dotn = 0.f;
#pragma unroll
        for (int j = 0; j < 4; ++j) {
          float ri = rr[j+1], rim1 = rr[j], rip1 = rr[j+2];
          float ui = up_r[j], um = j ? up_r[j-1] : um1c;
          float ybi = yb_r[j];
          float ybm = j ? yb_r[j-1] : ybm1;
          float ybp = (j < 3) ? yb_r[j+1] : ybp4;
          float Fbi = dt * (ybp - ybi);
          float Fbm = dt * (ybi - ybm);
          float wn = ybi;
          if (ui > 0.f)    wn += Fbi * ui;
          if (!(um > 0.f)) wn += Fbm * um;
          upbar[j] += Fbi * (ui > 0.f ? ri : rip1);
          float Fi = ui > 0.f ? ui * ri : ui * rip1;
          float Fm = um > 0.f ? um * rim1 : um * ri;
          dtb_part -= ybi * (Fi - Fm);
          if (h > 0) dotn += wn * ri;
          wreg[j] = wn;
        }
        if (h > 0) {
          float sgA = sgnf(y_r[h-1][0]), sgB = sgnf(y_r[h-1][3]);
          pairE[(h - 1) & 1][tid] = make_float4(sgA * wreg[0], sgA, sgB * wreg[3], sgB);
          dot = block_sum(dotn, red, tid, gen);
        }
      }
      float dtbar = block_sum(dtb_part, red, tid, gen);
      float md = mx + EPSF;
      float mbar = dtbar * (-CFL_ / (md * md));
      float tiesc = mbar / ntie;
#pragma unroll
      for (int j = 0; j < 4; ++j) {
        float ui = up_r[j];
        if (fabsf(ui) == mx) upbar[j] += tiesc * sgnf(ui);
      }
      // ---- up -= 0.1 * conv(LK^2, upbar); epilogue folds max + edge publish ----
      float accv[4];
      conv97(upbar, accv, cb, tid);
#pragma unroll
      for (int j = 0; j < 4; ++j) up_r[j] -= 0.1f * accv[j];
      upE3[tid] = up_r[3];
      {
        float mm = fmaxf(fmaxf(fabsf(up_r[0]), fabsf(up_r[1])),
                         fmaxf(fabsf(up_r[2]), fabsf(up_r[3])));
        mm = wave_max(mm);
        if ((tid & 63) == 0) red2[tid >> 6] = mm;
      }
      __syncthreads();
      float4 r2a = *(float4*)(red2), r2b = *(float4*)(red2 + 4);
      mx = rfl(fmaxf(fmaxf(fmaxf(r2a.x, r2a.y), fmaxf(r2a.z, r2a.w)),
                     fmaxf(fmaxf(r2b.x, r2b.y), fmaxf(r2b.z, r2b.w))));
      um1c = upE3[tm1];
    }
    // ---- outer: up already = leray(u_final); advect + normalize ----
    float dt = CFL_ / (mx + EPSF);
    float kap = (k == 0) ? 0.01f : ((k == 1) ? 0.005f : 0.0f);
    float rr[6];
    rr[0] = rhom1; rr[1] = rho_r[0]; rr[2] = rho_r[1];
    rr[3] = rho_r[2]; rr[4] = rho_r[3]; rr[5] = rhop4;
    float ylc[4]; float p2 = 0.f;
#pragma unroll
    for (int j = 0; j < 4; ++j) {
      float ri = rr[j+1], rim1 = rr[j], rip1 = rr[j+2];
      float ui = up_r[j], um = j ? up_r[j-1] : um1c;
      float Fi = ui > 0.f ? ui * ri : ui * rip1;
      float Fm = um > 0.f ? um * rim1 : um * ri;
      float yv = ri - dt * (Fi - Fm) + kap * dt * (rip1 + rim1 - 2.f * ri);
      ylc[j] = yv; p2 += fabsf(yv) + EPSF;
    }
    float s = block_sum(p2, red, tid, gen);
    float inv = 1.f / s;
#pragma unroll
    for (int j = 0; j < 4; ++j) rho_r[j] = (fabsf(ylc[j]) + EPSF) * inv;
  }
  // ---- final: rho_f = (rho + 0.1 v)/sum ----
  {
    float fl[4]; float part = 0.f;
#pragma unroll
    for (int j = 0; j < 4; ++j) {
      float f = rho_r[j] + 0.1f * v_r[j];
      fl[j] = f; part += f;
    }
    float s = block_sum(part, red, tid, gen);
    float inv = 1.f / s;
    *(float4*)(rho_f + b * NSEQ + 4 * tid) =
        make_float4(fl[0] * inv, fl[1] * inv, fl[2] * inv, fl[3] * inv);
  }
}

// ---------- kernel C: out = IDWT3(rho_f[:,:,None] * band_w[BAND_IDX]) ----------
__global__ __launch_bounds__(256) void kC(const float* __restrict__ rho_f,
                                          const float* __restrict__ bw,
                                          float* __restrict__ out) {
  const int blk = blockIdx.x;
  const int b = blk >> 8;
  const int g = blk & 255;
  __shared__ float q[8];
  if (threadIdx.x < 8) {
    int t = threadIdx.x;
    const float* rb = rho_f + b * NSEQ;
    float val;
    if (t == 0)      val = rb[g] * INV2R2;
    else if (t == 1) val = rb[256 + g] * INV2R2;
    else if (t < 4)  val = rb[512 + 2 * g + (t - 2)] * 0.5f;
    else             val = rb[1024 + 4 * g + (t - 4)] * INVR2;
    q[t] = val;
  }
  __syncthreads();
  float* ob = out + (((size_t)b * NSEQ) + (size_t)g * 8) * 2048;
  for (int c = threadIdx.x * 4; c < 2048; c += 1024) {
    float4 B0 = *(const float4*)(bw + c);
    float4 B1 = *(const float4*)(bw + 2048 + c);
    float4 B2 = *(const float4*)(bw + 4096 + c);
    float4 B3 = *(const float4*)(bw + 6144 + c);
    float b0[4] = {B0.x, B0.y, B0.z, B0.w};
    float b1[4] = {B1.x, B1.y, B1.z, B1.w};
    float b2[4] = {B2.x, B2.y, B2.z, B2.w};
    float b3[4] = {B3.x, B3.y, B3.z, B3.w};
    float o[8][4];
#pragma unroll
    for (int cc = 0; cc < 4; ++cc) {
      float pa = q[0] * b0[cc], pd3 = q[1] * b1[cc];
      float p2a = q[2] * b2[cc], p2b = q[3] * b2[cc];
      float e0 = pa + pd3, e1 = pa - pd3;
      float f0 = e0 + p2a, f1 = e0 - p2a, f2 = e1 + p2b, f3 = e1 - p2b;
      float g0 = q[4] * b3[cc], g1 = q[5] * b3[cc], g2 = q[6] * b3[cc], g3 = q[7] * b3[cc];
      o[0][cc] = f0 + g0; o[1][cc] = f0 - g0;
      o[2][cc] = f1 + g1; o[3][cc] = f1 - g1;
      o[4][cc] = f2 + g2; o[5][cc] = f2 - g2;
      o[6][cc] = f3 + g3; o[7][cc] = f3 - g3;
    }
#pragma unroll
    for (int j = 0; j < 8; ++j) {
      float4 t = make_float4(o[j][0], o[j][1], o[j][2], o[j][3]);
      *(float4*)(ob + (size_t)j * 2048 + c) = t;
    }
  }
}

extern "C" void kernel_launch(void* const* d_in, const int* in_sizes, int n_in,
                              void* d_out, int out_size, void* d_ws, size_t ws_size,
                              hipStream_t stream) {
  (void)in_sizes; (void)n_in; (void)out_size; (void)ws_size;
  const float* x   = (const float*)d_in[0];
  const float* wv  = (const float*)d_in[1];
  const float* phi = (const float*)d_in[2];
  const float* bw  = (const float*)d_in[3];
  float* out = (float*)d_out;
  float* rho_us = (float*)d_ws;
  float* pt     = rho_us + 8 * NSEQ;
  float* rho_f  = pt + 8 * NSEQ;

  kA<<<dim3(2048), dim3(256), 0, stream>>>(x, wv, rho_us, pt);
  kB<<<dim3(8), dim3(NT), 0, stream>>>(rho_us, pt, phi, rho_f);
  kC<<<dim3(2048), dim3(256), 0, stream>>>(rho_f, bw, out);
}

// Round 14
// 165.485 us; speedup vs baseline: 1.1876x; 1.0055x over previous
//
#include <hip/hip_runtime.h>
#include <math.h>

#define NSEQ 2048
#define EPSF 1e-8f
#define INV2R2 0.35355339059327373f
#define INVR2  0.7071067811865476f
#define NT 512   // HW law (r2/r5/r8/r9/r11): VGPR cap = 65536/B. 512 threads -> 128 regs.

// ---------- compile-time Leray conv taps ----------
// K = -0.5*sum M^i (50 Jacobi iters), LK = delta - 2nd-diff(K) (support |o|<=50).
// lk65: LK truncated to radius 32 (tail ~3e-6, validated r5+).
// lk2:  (LK*LK) truncated to radius 40 — exact double conv of untruncated LK;
//       tail-L1 beyond 40 ~4e-6, same scale as the validated lk65 tail.
struct TapsAll { float lk65[65]; float lk2[81]; };

constexpr TapsAll make_taps() {
  TapsAll t{};
  double K[99] = {};
  for (int j = -49; j <= 49; ++j) {
    int aj = j < 0 ? -j : j;
    double term = 1.0;
    for (int q = 0; q < aj; ++q) term *= 0.5;
    double sum = term;
    for (int i = aj + 2; i <= 49; i += 2) {
      int m = (i + j) / 2;
      term *= (double)((i - 1) * i) / (4.0 * (double)m * (double)(i - m));
      sum += term;
    }
    K[j + 49] = -0.5 * sum;
  }
  double LKd[101] = {};
  for (int o = -50; o <= 50; ++o) {
    double km1 = (o - 1 >= -49 && o - 1 <= 49) ? K[o - 1 + 49] : 0.0;
    double k0  = (o     >= -49 && o     <= 49) ? K[o + 49]     : 0.0;
    double kp1 = (o + 1 >= -49 && o + 1 <= 49) ? K[o + 1 + 49] : 0.0;
    LKd[o + 50] = ((o == 0) ? 1.0 : 0.0) - (kp1 - 2.0 * k0 + km1);
  }
  for (int o = -32; o <= 32; ++o) t.lk65[o + 32] = (float)LKd[o + 50];
  for (int o = -40; o <= 40; ++o) {
    double s = 0.0;
    int alo = (o - 50 > -50) ? o - 50 : -50;
    int ahi = (o + 50 <  50) ? o + 50 :  50;
    for (int a = alo; a <= ahi; ++a) s += LKd[a + 50] * LKd[o - a + 50];
    t.lk2[o + 40] = (float)s;
  }
  return t;
}
constexpr TapsAll TAPS = make_taps();

// ---------- uniform-scalar pin: value identical across lanes -> SGPR ----------
__device__ __forceinline__ float rfl(float x) {
  return __int_as_float(__builtin_amdgcn_readfirstlane(__float_as_int(x)));
}

// ---------- reduction helpers (512 threads = 8 waves) ----------
__device__ __forceinline__ float wave_sum(float x) {
#pragma unroll
  for (int m = 1; m < 64; m <<= 1) x += __shfl_xor(x, m, 64);
  return x;
}
__device__ __forceinline__ float wave_max(float x) {
#pragma unroll
  for (int m = 1; m < 64; m <<= 1) x = fmaxf(x, __shfl_xor(x, m, 64));
  return x;
}
__device__ __forceinline__ float block_sum(float x, float* red, int tid, int& gen) {
  float w = wave_sum(x);
  int slot = (gen & 7) << 5; gen++;
  if ((tid & 63) == 0) red[slot + (tid >> 6)] = w;
  __syncthreads();
  float4 a = *(float4*)(red + slot), b = *(float4*)(red + slot + 4);
  return rfl(((a.x + a.y) + (a.z + a.w)) + ((b.x + b.y) + (b.z + b.w)));
}
__device__ __forceinline__ void block_sum2(float a, float b, float* red, int tid, int& gen,
                                           float& oa, float& ob) {
  float wa = wave_sum(a), wb = wave_sum(b);
  int slot = (gen & 7) << 5; gen++;
  if ((tid & 63) == 0) { int w = tid >> 6; red[slot + w] = wa; red[slot + 16 + w] = wb; }
  __syncthreads();
  float4 a0 = *(float4*)(red + slot),      a1 = *(float4*)(red + slot + 4);
  float4 b0 = *(float4*)(red + slot + 16), b1 = *(float4*)(red + slot + 20);
  oa = rfl(((a0.x + a0.y) + (a0.z + a0.w)) + ((a1.x + a1.y) + (a1.z + a1.w)));
  ob = rfl(((b0.x + b0.y) + (b0.z + b0.w)) + ((b1.x + b1.y) + (b1.z + b1.w)));
}
__device__ __forceinline__ float sgnf(float x) {
  return (x > 0.f) ? 1.f : ((x < 0.f) ? -1.f : 0.f);
}

// ---------- 65-tap conv (radius 32, LK): used once for up0 ----------
__device__ __forceinline__ void conv65(const float in[4], float acc[4],
                                       float* __restrict__ cb, int tid) {
  *(float4*)(cb + (tid << 2)) = make_float4(in[0], in[1], in[2], in[3]);
  __syncthreads();
  const int base = tid << 2;
  acc[0] = 0.f; acc[1] = 0.f; acc[2] = 0.f; acc[3] = 0.f;
#pragma unroll
  for (int m = 0; m < 17; ++m) {
    const int idx = (base - 32 + 4 * m) & (NSEQ - 1);
    const float4 c4 = *(const float4*)(cb + idx);
    const float cv[4] = {c4.x, c4.y, c4.z, c4.w};
#pragma unroll
    for (int jj = 0; jj < 4; ++jj) {
      const int d = 4 * m + jj;
#pragma unroll
      for (int j = 0; j < 4; ++j) {
        const int o = d - 32 - j;
        if (o >= -32 && o <= 32) acc[j] = fmaf(TAPS.lk65[o + 32], cv[jj], acc[j]);
      }
    }
  }
}

// ---------- 81-tap window accumulate (radius 40, LK^2); staging done by caller ----------
__device__ __forceinline__ void conv81_read(float acc[4], const float* __restrict__ cb,
                                            int tid) {
  const int base = tid << 2;
  acc[0] = 0.f; acc[1] = 0.f; acc[2] = 0.f; acc[3] = 0.f;
#pragma unroll
  for (int m = 0; m < 21; ++m) {
    const int idx = (base - 40 + 4 * m) & (NSEQ - 1);
    const float4 c4 = *(const float4*)(cb + idx);
    const float cv[4] = {c4.x, c4.y, c4.z, c4.w};
#pragma unroll
    for (int jj = 0; jj < 4; ++jj) {
      const int d = 4 * m + jj;
#pragma unroll
      for (int j = 0; j < 4; ++j) {
        const int o = d - 40 - j;
        if (o >= -40 && o <= 40) acc[j] = fmaf(TAPS.lk2[o + 40], cv[jj], acc[j]);
      }
    }
  }
}

// ---------- kernel A: rho_unscaled (L2 of DWT rows) + per_token ----------
__global__ __launch_bounds__(256) void kA(const float* __restrict__ x,
                                          const float* __restrict__ wv,
                                          float* __restrict__ rho_us,
                                          float* __restrict__ pt) {
  const int blk = blockIdx.x;
  const int b = blk >> 8;
  const int g = blk & 255;
  const float* xb = x + (((size_t)b * NSEQ) + (size_t)g * 8) * 2048;
  const int tid = threadIdx.x;
  float sq[8] = {0.f, 0.f, 0.f, 0.f, 0.f, 0.f, 0.f, 0.f};
  float pp[8] = {0.f, 0.f, 0.f, 0.f, 0.f, 0.f, 0.f, 0.f};
  for (int c = tid * 4; c < 2048; c += 1024) {
    float4 w4 = *(const float4*)(wv + c);
    float wj[4] = {w4.x, w4.y, w4.z, w4.w};
    float xv[8][4];
#pragma unroll
    for (int r = 0; r < 8; ++r) {
      float4 t = *(const float4*)(xb + (size_t)r * 2048 + c);
      xv[r][0] = t.x; xv[r][1] = t.y; xv[r][2] = t.z; xv[r][3] = t.w;
    }
#pragma unroll
    for (int j = 0; j < 4; ++j) {
      float x0 = xv[0][j], x1 = xv[1][j], x2 = xv[2][j], x3 = xv[3][j];
      float x4 = xv[4][j], x5 = xv[5][j], x6 = xv[6][j], x7 = xv[7][j];
      float t01 = x0 + x1, t23 = x2 + x3, t45 = x4 + x5, t67 = x6 + x7;
      float a = t01 + t23, bb = t45 + t67;
      float c3 = a + bb, d3 = a - bb, d2a = t01 - t23, d2b = t45 - t67;
      float d10 = x0 - x1, d11 = x2 - x3, d12 = x4 - x5, d13 = x6 - x7;
      sq[0] += c3 * c3;  sq[1] += d3 * d3;  sq[2] += d2a * d2a; sq[3] += d2b * d2b;
      sq[4] += d10 * d10; sq[5] += d11 * d11; sq[6] += d12 * d12; sq[7] += d13 * d13;
      float w = wj[j];
      pp[0] += x0 * w; pp[1] += x1 * w; pp[2] += x2 * w; pp[3] += x3 * w;
      pp[4] += x4 * w; pp[5] += x5 * w; pp[6] += x6 * w; pp[7] += x7 * w;
    }
  }
  __shared__ float sred[4][16];
  float vals[16];
#pragma unroll
  for (int q = 0; q < 8; ++q) vals[q] = sq[q];
#pragma unroll
  for (int q = 0; q < 8; ++q) vals[8 + q] = pp[q];
#pragma unroll
  for (int q = 0; q < 16; ++q) vals[q] = wave_sum(vals[q]);
  int lane = tid & 63, wid = tid >> 6;
  if (lane == 0) {
#pragma unroll
    for (int q = 0; q < 16; ++q) sred[wid][q] = vals[q];
  }
  __syncthreads();
  if (tid < 16) {
    float s = sred[0][tid] + sred[1][tid] + sred[2][tid] + sred[3][tid];
    if (tid < 8) {
      float scale = (tid < 2) ? 0.125f : ((tid < 4) ? 0.25f : 0.5f);
      int pos = (tid == 0) ? g : (tid == 1) ? (256 + g)
               : (tid < 4) ? (512 + 2 * g + (tid - 2)) : (1024 + 4 * g + (tid - 4));
      rho_us[b * NSEQ + pos] = sqrtf(s * scale);
    } else {
      pt[b * NSEQ + 8 * g + (tid - 8)] = s;
    }
  }
}

// ---------- kernel B: serial dynamics; 512 threads, 4 contiguous elems/thread ----------
__global__ __launch_bounds__(NT) void kB(const float* __restrict__ rho_us,
                                         const float* __restrict__ pt,
                                         const float* __restrict__ phi,
                                         float* __restrict__ rho_f) {
  __shared__ float cb[NSEQ];                    // conv staging (single buffer)
  __shared__ float up0M[NSEQ];                  // up0 = leray(grad1 v), cached in LDS
  __shared__ float vE0[NT];
  __shared__ float rhoE0[NT], rhoE3[NT];        // hold UNNORMALIZED tl during reaction
  __shared__ float upE3[NT];
  __shared__ float yE0[3][NT], yE3[3][NT];
  __shared__ float4 pairE[2][NT];               // (sgw0,sg0,sgw3,sg3), by h-parity
  __shared__ float red[256];
  __shared__ float red2[16];                    // [0..7] max partials, [8..15] dtbar partials
  __shared__ int   tieBufI[NSEQ];               // tie list: pos | (sign<<16)
  __shared__ int   tieCnt;

  const int tid = threadIdx.x;
  const int b = blockIdx.x;
  const int tm1 = (tid - 1) & (NT - 1);
  const int tp1 = (tid + 1) & (NT - 1);
  int gen = 0;
  const float CFL_ = 0.4f;

  if (tid == 0) tieCnt = 0;

  // reaction only ever needs exp(-0.1*phi): hoist it.
  float4 phv = *(const float4*)(phi + 4 * tid);
  float ephi[4] = {__expf(-0.1f * phv.x), __expf(-0.1f * phv.y),
                   __expf(-0.1f * phv.z), __expf(-0.1f * phv.w)};

  // ---- v = normalize(|dwt1d(per_token)| * sqrt(D)) ----
  float v_r[4];
  {
    const float* ptb = pt + b * NSEQ;
    float vl[4]; float part = 0.f;
#pragma unroll
    for (int j = 0; j < 4; ++j) {
      float c;
      if (tid < 64) {
        int r = (4 * tid + j) * 8;
        float t01 = ptb[r] + ptb[r+1], t23 = ptb[r+2] + ptb[r+3];
        float t45 = ptb[r+4] + ptb[r+5], t67 = ptb[r+6] + ptb[r+7];
        c = ((t01 + t23) + (t45 + t67)) * INV2R2;
      } else if (tid < 128) {
        int r = (4 * (tid - 64) + j) * 8;
        float t01 = ptb[r] + ptb[r+1], t23 = ptb[r+2] + ptb[r+3];
        float t45 = ptb[r+4] + ptb[r+5], t67 = ptb[r+6] + ptb[r+7];
        c = ((t01 + t23) - (t45 + t67)) * INV2R2;
      } else if (tid < 256) {
        int r = (4 * (tid - 128) + j) * 4;
        c = ((ptb[r] + ptb[r+1]) - (ptb[r+2] + ptb[r+3])) * 0.5f;
      } else {
        int r = (4 * (tid - 256) + j) * 2;
        c = (ptb[r] - ptb[r+1]) * INVR2;
      }
      float val = sqrtf(2048.0f * c * c) + EPSF;
      vl[j] = val; part += val;
    }
    float sv = block_sum(part, red, tid, gen);
    float inv = 1.0f / sv;
#pragma unroll
    for (int j = 0; j < 4; ++j) v_r[j] = vl[j] * inv;
    vE0[tid] = v_r[0];
  }
  // ---- rho = normalize(rho_us) ----
  float rho_r[4];
  {
    float4 rv = *(const float4*)(rho_us + b * NSEQ + 4 * tid);
    float rl[4] = {rv.x + EPSF, rv.y + EPSF, rv.z + EPSF, rv.w + EPSF};
    float part = rl[0] + rl[1] + rl[2] + rl[3];
    float sr = block_sum(part, red, tid, gen);   // barrier publishes vE0
    float inv = 1.f / sr;
#pragma unroll
    for (int j = 0; j < 4; ++j) rho_r[j] = rl[j] * inv;
  }

  // ---- up0 = leray(grad1(v)) : computed ONCE, cached in LDS for every outer k ----
  float up_r[4];
  float mx, mx0, um1c;
  {
    float vp4c = vE0[tp1];
    float u0[4] = {v_r[1] - v_r[0], v_r[2] - v_r[1], v_r[3] - v_r[2], vp4c - v_r[3]};
    conv65(u0, up_r, cb, tid);
    *(float4*)(up0M + (tid << 2)) = make_float4(up_r[0], up_r[1], up_r[2], up_r[3]);
    float mm = fmaxf(fmaxf(fabsf(up_r[0]), fabsf(up_r[1])),
                     fmaxf(fabsf(up_r[2]), fabsf(up_r[3])));
    mm = wave_max(mm);
    if ((tid & 63) == 0) red2[tid >> 6] = mm;
    __syncthreads();
    float4 r2a = *(float4*)(red2), r2b = *(float4*)(red2 + 4);
    mx = rfl(fmaxf(fmaxf(fmaxf(r2a.x, r2a.y), fmaxf(r2a.z, r2a.w)),
                   fmaxf(fmaxf(r2b.x, r2b.y), fmaxf(r2b.z, r2b.w))));
    um1c = up0M[(4 * tid - 1) & (NSEQ - 1)];
    mx0 = mx;
  }

  for (int k = 0; k < 3; ++k) {
    // ---- reaction (fast exp/log); unnormalized tl published pre-barrier ----
    float rhom1, rhop4;
    {
      float tl[4]; float part = 0.f;
#pragma unroll
      for (int j = 0; j < 4; ++j) {
        float r = rho_r[j];
        float t = r * ephi[j] * __expf(-0.1f * __logf(r));
        float t2 = fabsf(t) + EPSF;
        tl[j] = t2; part += t2;
      }
      rhoE0[tid] = tl[0]; rhoE3[tid] = tl[3];    // published by the sum barrier
      float s = block_sum(part, red, tid, gen);
      float inv = 1.f / s;
#pragma unroll
      for (int j = 0; j < 4; ++j) rho_r[j] = tl[j] * inv;
      rhom1 = rhoE3[tm1] * inv;                  // identical math to neighbor's rho
      rhop4 = rhoE0[tp1] * inv;
    }
    if (k > 0) {                           // u = grad1(v) identical every k -> reuse up0
      float4 u4 = *(const float4*)(up0M + (tid << 2));
      up_r[0] = u4.x; up_r[1] = u4.y; up_r[2] = u4.z; up_r[3] = u4.w;
      um1c = up0M[(4 * tid - 1) & (NSEQ - 1)];
      mx = mx0;
    }

    float y_r[4][4];
    for (int step = 0; step < 5; ++step) {
      float dt = CFL_ / (mx + EPSF);
      // ---- forward rollout (ntie in h=0, cost-dot in h=3, passA(3) mirrored) ----
      float sarr[4]; float spv = 1.f; float ntie = 1.f, dot = 0.f;
#pragma unroll
      for (int h = 0; h < 4; ++h) {
        float invp = 1.f / spv;
        float rr[6];
        if (h == 0) {
          rr[0] = rhom1; rr[1] = rho_r[0]; rr[2] = rho_r[1];
          rr[3] = rho_r[2]; rr[4] = rho_r[3]; rr[5] = rhop4;
        } else {
          rr[0] = (fabsf(yE3[h-1][tm1]) + EPSF) * invp;
#pragma unroll
          for (int j = 0; j < 4; ++j) rr[j+1] = (fabsf(y_r[h-1][j]) + EPSF) * invp;
          rr[5] = (fabsf(yE0[h-1][tp1]) + EPSF) * invp;
        }
        float part2 = 0.f, aux = 0.f;
#pragma unroll
        for (int j = 0; j < 4; ++j) {
          float ri = rr[j+1], rim1 = rr[j], rip1 = rr[j+2];
          float ui = up_r[j], um = j ? up_r[j-1] : um1c;
          float Fi = ui > 0.f ? ui * ri : ui * rip1;
          float Fm = um > 0.f ? um * rim1 : um * ri;
          float yv = ri - dt * (Fi - Fm);
          y_r[h][j] = yv;
          float ayv = fabsf(yv) + EPSF;
          part2 += ayv;
          if (h == 0) aux += (fabsf(ui) == mx) ? 1.f : 0.f;
          if (h == 3) aux += (1.f - v_r[j]) * 0.125f * ayv;
        }
        if (h < 3) { yE0[h][tid] = y_r[h][0]; yE3[h][tid] = y_r[h][3]; }
        if (h == 3) {
          float sg0 = sgnf(y_r[3][0]), sg3 = sgnf(y_r[3][3]);
          pairE[1][tid] = make_float4(sg0 * (1.f - v_r[0]) * 0.125f, sg0,
                                      sg3 * (1.f - v_r[3]) * 0.125f, sg3);
        }
        if (h == 0) { float o1, o2; block_sum2(part2, aux, red, tid, gen, o1, o2); sarr[0] = o1; ntie = o2; }
        else if (h == 3) { float o1, o2; block_sum2(part2, aux, red, tid, gen, o1, o2); sarr[3] = o1; dot = o2 / o1; }
        else sarr[h] = block_sum(part2, red, tid, gen);
        spv = sarr[h];
      }
      // ---- backward (passA folded into dot barriers via pairE mirrors) ----
      float wreg[4], upbar[4];
#pragma unroll
      for (int j = 0; j < 4; ++j) { wreg[j] = (1.f - v_r[j]) * 0.125f; upbar[j] = 0.f; }
      float dtb_part = 0.f;
#pragma unroll
      for (int h = 3; h >= 0; --h) {
        float invst = 1.f / sarr[h];
        float invp = (h > 0) ? 1.f / sarr[h-1] : 0.f;
        const int bo = h & 1;
        float yb_r[4];
#pragma unroll
        for (int j = 0; j < 4; ++j)
          yb_r[j] = sgnf(y_r[h][j]) * (wreg[j] - dot) * invst;
        float4 pm = pairE[bo][tm1], pp = pairE[bo][tp1];
        float ybm1 = (pm.z - dot * pm.w) * invst;
        float ybp4 = (pp.x - dot * pp.y) * invst;
        float rr[6];
        if (h == 0) {
          rr[0] = rhom1; rr[1] = rho_r[0]; rr[2] = rho_r[1];
          rr[3] = rho_r[2]; rr[4] = rho_r[3]; rr[5] = rhop4;
        } else {
          rr[0] = (fabsf(yE3[h-1][tm1]) + EPSF) * invp;
#pragma unroll
          for (int j = 0; j < 4; ++j) rr[j+1] = (fabsf(y_r[h-1][j]) + EPSF) * invp;
          rr[5] = (fabsf(yE0[h-1][tp1]) + EPSF) * invp;
        }
        float dotn = 0.f;
#pragma unroll
        for (int j = 0; j < 4; ++j) {
          float ri = rr[j+1], rim1 = rr[j], rip1 = rr[j+2];
          float ui = up_r[j], um = j ? up_r[j-1] : um1c;
          float ybi = yb_r[j];
          float ybm = j ? yb_r[j-1] : ybm1;
          float ybp = (j < 3) ? yb_r[j+1] : ybp4;
          float Fbi = dt * (ybp - ybi);
          float Fbm = dt * (ybi - ybm);
          float wn = ybi;
          if (ui > 0.f)    wn += Fbi * ui;
          if (!(um > 0.f)) wn += Fbm * um;
          upbar[j] += Fbi * (ui > 0.f ? ri : rip1);
          float Fi = ui > 0.f ? ui * ri : ui * rip1;
          float Fm = um > 0.f ? um * rim1 : um * ri;
          dtb_part -= ybi * (Fi - Fm);
          if (h > 0) dotn += wn * ri;
          wreg[j] = wn;
        }
        if (h > 0) {
          float sgA = sgnf(y_r[h-1][0]), sgB = sgnf(y_r[h-1][3]);
          pairE[(h - 1) & 1][tid] = make_float4(sgA * wreg[0], sgA, sgB * wreg[3], sgB);
          dot = block_sum(dotn, red, tid, gen);
        }
      }
      // ---- stage phase: cb <- upbar (pre-tie), dtbar partials, tie list ----
      *(float4*)(cb + (tid << 2)) = make_float4(upbar[0], upbar[1], upbar[2], upbar[3]);
      {
        float w = wave_sum(dtb_part);
        if ((tid & 63) == 0) red2[8 + (tid >> 6)] = w;
      }
#pragma unroll
      for (int j = 0; j < 4; ++j) {
        float ui = up_r[j];
        if (fabsf(ui) == mx) {
          int ix = atomicAdd(&tieCnt, 1);
          tieBufI[ix] = (4 * tid + j) | ((ui < 0.f) ? 0x10000 : 0);
        }
      }
      __syncthreads();
      // ---- conv-read phase: conv(LK2, upbar_pre) + tiesc * conv(LK2, T) ----
      float4 r2c = *(float4*)(red2 + 8), r2d = *(float4*)(red2 + 12);
      float dtbar = rfl(((r2c.x + r2c.y) + (r2c.z + r2c.w)) +
                        ((r2d.x + r2d.y) + (r2d.z + r2d.w)));
      float md = mx + EPSF;
      float tiesc = (dtbar * (-CFL_ / (md * md))) / ntie;
      float accv[4];
      conv81_read(accv, cb, tid);
      int nt = (int)(ntie + 0.5f);
      for (int e = 0; e < nt; ++e) {
        int ent = tieBufI[e];
        int p = ent & 0xFFFF;
        float sg = (ent & 0x10000) ? -tiesc : tiesc;
#pragma unroll
        for (int j = 0; j < 4; ++j) {
          int d = ((4 * tid + j) - p) & (NSEQ - 1);
          int ds = (d >= 1024) ? d - 2048 : d;
          if (ds >= -40 && ds <= 40) accv[j] = fmaf(sg, TAPS.lk2[ds + 40], accv[j]);
        }
      }
#pragma unroll
      for (int j = 0; j < 4; ++j) up_r[j] -= 0.1f * accv[j];
      upE3[tid] = up_r[3];
      {
        float mm = fmaxf(fmaxf(fabsf(up_r[0]), fabsf(up_r[1])),
                         fmaxf(fabsf(up_r[2]), fabsf(up_r[3])));
        mm = wave_max(mm);
        if ((tid & 63) == 0) red2[tid >> 6] = mm;
      }
      if (tid == 0) tieCnt = 0;
      __syncthreads();
      float4 r2a = *(float4*)(red2), r2b = *(float4*)(red2 + 4);
      mx = rfl(fmaxf(fmaxf(fmaxf(r2a.x, r2a.y), fmaxf(r2a.z, r2a.w)),
                     fmaxf(fmaxf(r2b.x, r2b.y), fmaxf(r2b.z, r2b.w))));
      um1c = upE3[tm1];
    }
    // ---- outer: up already = leray(u_final); advect + normalize ----
    float dt = CFL_ / (mx + EPSF);
    float kap = (k == 0) ? 0.01f : ((k == 1) ? 0.005f : 0.0f);
    float rr[6];
    rr[0] = rhom1; rr[1] = rho_r[0]; rr[2] = rho_r[1];
    rr[3] = rho_r[2]; rr[4] = rho_r[3]; rr[5] = rhop4;
    float ylc[4]; float p2 = 0.f;
#pragma unroll
    for (int j = 0; j < 4; ++j) {
      float ri = rr[j+1], rim1 = rr[j], rip1 = rr[j+2];
      float ui = up_r[j], um = j ? up_r[j-1] : um1c;
      float Fi = ui > 0.f ? ui * ri : ui * rip1;
      float Fm = um > 0.f ? um * rim1 : um * ri;
      float yv = ri - dt * (Fi - Fm) + kap * dt * (rip1 + rim1 - 2.f * ri);
      ylc[j] = yv; p2 += fabsf(yv) + EPSF;
    }
    float s = block_sum(p2, red, tid, gen);
    float inv = 1.f / s;
#pragma unroll
    for (int j = 0; j < 4; ++j) rho_r[j] = (fabsf(ylc[j]) + EPSF) * inv;
  }
  // ---- final: rho_f = (rho + 0.1 v)/sum ----
  {
    float fl[4]; float part = 0.f;
#pragma unroll
    for (int j = 0; j < 4; ++j) {
      float f = rho_r[j] + 0.1f * v_r[j];
      fl[j] = f; part += f;
    }
    float s = block_sum(part, red, tid, gen);
    float inv = 1.f / s;
    *(float4*)(rho_f + b * NSEQ + 4 * tid) =
        make_float4(fl[0] * inv, fl[1] * inv, fl[2] * inv, fl[3] * inv);
  }
}

// ---------- kernel C: out = IDWT3(rho_f[:,:,None] * band_w[BAND_IDX]) ----------
__global__ __launch_bounds__(256) void kC(const float* __restrict__ rho_f,
                                          const float* __restrict__ bw,
                                          float* __restrict__ out) {
  const int blk = blockIdx.x;
  const int b = blk >> 8;
  const int g = blk & 255;
  __shared__ float q[8];
  if (threadIdx.x < 8) {
    int t = threadIdx.x;
    const float* rb = rho_f + b * NSEQ;
    float val;
    if (t == 0)      val = rb[g] * INV2R2;
    else if (t == 1) val = rb[256 + g] * INV2R2;
    else if (t < 4)  val = rb[512 + 2 * g + (t - 2)] * 0.5f;
    else             val = rb[1024 + 4 * g + (t - 4)] * INVR2;
    q[t] = val;
  }
  __syncthreads();
  float* ob = out + (((size_t)b * NSEQ) + (size_t)g * 8) * 2048;
  for (int c = threadIdx.x * 4; c < 2048; c += 1024) {
    float4 B0 = *(const float4*)(bw + c);
    float4 B1 = *(const float4*)(bw + 2048 + c);
    float4 B2 = *(const float4*)(bw + 4096 + c);
    float4 B3 = *(const float4*)(bw + 6144 + c);
    float b0[4] = {B0.x, B0.y, B0.z, B0.w};
    float b1[4] = {B1.x, B1.y, B1.z, B1.w};
    float b2[4] = {B2.x, B2.y, B2.z, B2.w};
    float b3[4] = {B3.x, B3.y, B3.z, B3.w};
    float o[8][4];
#pragma unroll
    for (int cc = 0; cc < 4; ++cc) {
      float pa = q[0] * b0[cc], pd3 = q[1] * b1[cc];
      float p2a = q[2] * b2[cc], p2b = q[3] * b2[cc];
      float e0 = pa + pd3, e1 = pa - pd3;
      float f0 = e0 + p2a, f1 = e0 - p2a, f2 = e1 + p2b, f3 = e1 - p2b;
      float g0 = q[4] * b3[cc], g1 = q[5] * b3[cc], g2 = q[6] * b3[cc], g3 = q[7] * b3[cc];
      o[0][cc] = f0 + g0; o[1][cc] = f0 - g0;
      o[2][cc] = f1 + g1; o[3][cc] = f1 - g1;
      o[4][cc] = f2 + g2; o[5][cc] = f2 - g2;
      o[6][cc] = f3 + g3; o[7][cc] = f3 - g3;
    }
#pragma unroll
    for (int j = 0; j < 8; ++j) {
      float4 t = make_float4(o[j][0], o[j][1], o[j][2], o[j][3]);
      *(float4*)(ob + (size_t)j * 2048 + c) = t;
    }
  }
}

extern "C" void kernel_launch(void* const* d_in, const int* in_sizes, int n_in,
                              void* d_out, int out_size, void* d_ws, size_t ws_size,
                              hipStream_t stream) {
  (void)in_sizes; (void)n_in; (void)out_size; (void)ws_size;
  const float* x   = (const float*)d_in[0];
  const float* wv  = (const float*)d_in[1];
  const float* phi = (const float*)d_in[2];
  const float* bw  = (const float*)d_in[3];
  float* out = (float*)d_out;
  float* rho_us = (float*)d_ws;
  float* pt     = rho_us + 8 * NSEQ;
  float* rho_f  = pt + 8 * NSEQ;

  kA<<<dim3(2048), dim3(256), 0, stream>>>(x, wv, rho_us, pt);
  kB<<<dim3(8), dim3(NT), 0, stream>>>(rho_us, pt, phi, rho_f);
  kC<<<dim3(2048), dim3(256), 0, stream>>>(rho_f, bw, out);
}

// Round 15
// 164.229 us; speedup vs baseline: 1.1967x; 1.0076x over previous
//
#include <hip/hip_runtime.h>
#include <math.h>

#define NSEQ 2048
#define EPSF 1e-8f
#define INV2R2 0.35355339059327373f
#define INVR2  0.7071067811865476f
#define SQRT2048 45.254833995939045f
#define NT 512   // HW law (r2/r5/r8/r9/r11): VGPR cap = 65536/B. 512 threads -> 128 regs.

// ---------- compile-time Leray conv taps ----------
// K = -0.5*sum M^i (50 Jacobi iters), LK = delta - 2nd-diff(K) (support |o|<=50).
// lk65: LK truncated to radius 32 (tail ~3e-6, validated r5+).
// lk2:  (LK*LK) truncated to radius 40 — exact double conv of untruncated LK;
//       tail-L1 beyond 40 ~4e-6 (validated r14).
struct TapsAll { float lk65[65]; float lk2[81]; };

constexpr TapsAll make_taps() {
  TapsAll t{};
  double K[99] = {};
  for (int j = -49; j <= 49; ++j) {
    int aj = j < 0 ? -j : j;
    double term = 1.0;
    for (int q = 0; q < aj; ++q) term *= 0.5;
    double sum = term;
    for (int i = aj + 2; i <= 49; i += 2) {
      int m = (i + j) / 2;
      term *= (double)((i - 1) * i) / (4.0 * (double)m * (double)(i - m));
      sum += term;
    }
    K[j + 49] = -0.5 * sum;
  }
  double LKd[101] = {};
  for (int o = -50; o <= 50; ++o) {
    double km1 = (o - 1 >= -49 && o - 1 <= 49) ? K[o - 1 + 49] : 0.0;
    double k0  = (o     >= -49 && o     <= 49) ? K[o + 49]     : 0.0;
    double kp1 = (o + 1 >= -49 && o + 1 <= 49) ? K[o + 1 + 49] : 0.0;
    LKd[o + 50] = ((o == 0) ? 1.0 : 0.0) - (kp1 - 2.0 * k0 + km1);
  }
  for (int o = -32; o <= 32; ++o) t.lk65[o + 32] = (float)LKd[o + 50];
  for (int o = -40; o <= 40; ++o) {
    double s = 0.0;
    int alo = (o - 50 > -50) ? o - 50 : -50;
    int ahi = (o + 50 <  50) ? o + 50 :  50;
    for (int a = alo; a <= ahi; ++a) s += LKd[a + 50] * LKd[o - a + 50];
    t.lk2[o + 40] = (float)s;
  }
  return t;
}
constexpr TapsAll TAPS = make_taps();

// ---------- uniform-scalar pin: value identical across lanes -> SGPR ----------
__device__ __forceinline__ float rfl(float x) {
  return __int_as_float(__builtin_amdgcn_readfirstlane(__float_as_int(x)));
}

// ---------- reduction helpers (512 threads = 8 waves) ----------
__device__ __forceinline__ float wave_sum(float x) {
#pragma unroll
  for (int m = 1; m < 64; m <<= 1) x += __shfl_xor(x, m, 64);
  return x;
}
__device__ __forceinline__ float wave_max(float x) {
#pragma unroll
  for (int m = 1; m < 64; m <<= 1) x = fmaxf(x, __shfl_xor(x, m, 64));
  return x;
}
__device__ __forceinline__ float block_sum(float x, float* red, int tid, int& gen) {
  float w = wave_sum(x);
  int slot = (gen & 7) << 5; gen++;
  if ((tid & 63) == 0) red[slot + (tid >> 6)] = w;
  __syncthreads();
  float4 a = *(float4*)(red + slot), b = *(float4*)(red + slot + 4);
  return rfl(((a.x + a.y) + (a.z + a.w)) + ((b.x + b.y) + (b.z + b.w)));
}
__device__ __forceinline__ void block_sum2(float a, float b, float* red, int tid, int& gen,
                                           float& oa, float& ob) {
  float wa = wave_sum(a), wb = wave_sum(b);
  int slot = (gen & 7) << 5; gen++;
  if ((tid & 63) == 0) { int w = tid >> 6; red[slot + w] = wa; red[slot + 16 + w] = wb; }
  __syncthreads();
  float4 a0 = *(float4*)(red + slot),      a1 = *(float4*)(red + slot + 4);
  float4 b0 = *(float4*)(red + slot + 16), b1 = *(float4*)(red + slot + 20);
  oa = rfl(((a0.x + a0.y) + (a0.z + a0.w)) + ((a1.x + a1.y) + (a1.z + a1.w)));
  ob = rfl(((b0.x + b0.y) + (b0.z + b0.w)) + ((b1.x + b1.y) + (b1.z + b1.w)));
}
__device__ __forceinline__ float sgnf(float x) {
  return (x > 0.f) ? 1.f : ((x < 0.f) ? -1.f : 0.f);
}

// ---------- 65-tap conv (radius 32, LK): used once for up0 ----------
__device__ __forceinline__ void conv65(const float in[4], float acc[4],
                                       float* __restrict__ cb, int tid) {
  *(float4*)(cb + (tid << 2)) = make_float4(in[0], in[1], in[2], in[3]);
  __syncthreads();
  const int base = tid << 2;
  acc[0] = 0.f; acc[1] = 0.f; acc[2] = 0.f; acc[3] = 0.f;
#pragma unroll
  for (int m = 0; m < 17; ++m) {
    const int idx = (base - 32 + 4 * m) & (NSEQ - 1);
    const float4 c4 = *(const float4*)(cb + idx);
    const float cv[4] = {c4.x, c4.y, c4.z, c4.w};
#pragma unroll
    for (int jj = 0; jj < 4; ++jj) {
      const int d = 4 * m + jj;
#pragma unroll
      for (int j = 0; j < 4; ++j) {
        const int o = d - 32 - j;
        if (o >= -32 && o <= 32) acc[j] = fmaf(TAPS.lk65[o + 32], cv[jj], acc[j]);
      }
    }
  }
}

// ---------- 81-tap window accumulate (radius 40, LK^2); staging done by caller ----------
__device__ __forceinline__ void conv81_read(float acc[4], const float* __restrict__ cb,
                                            int tid) {
  const int base = tid << 2;
  acc[0] = 0.f; acc[1] = 0.f; acc[2] = 0.f; acc[3] = 0.f;
#pragma unroll
  for (int m = 0; m < 21; ++m) {
    const int idx = (base - 40 + 4 * m) & (NSEQ - 1);
    const float4 c4 = *(const float4*)(cb + idx);
    const float cv[4] = {c4.x, c4.y, c4.z, c4.w};
#pragma unroll
    for (int jj = 0; jj < 4; ++jj) {
      const int d = 4 * m + jj;
#pragma unroll
      for (int j = 0; j < 4; ++j) {
        const int o = d - 40 - j;
        if (o >= -40 && o <= 40) acc[j] = fmaf(TAPS.lk2[o + 40], cv[jj], acc[j]);
      }
    }
  }
}

// ---------- kernel A: rho_unscaled (L2 of DWT rows) + per_token ----------
__global__ __launch_bounds__(256) void kA(const float* __restrict__ x,
                                          const float* __restrict__ wv,
                                          float* __restrict__ rho_us,
                                          float* __restrict__ pt) {
  const int blk = blockIdx.x;
  const int b = blk >> 8;
  const int g = blk & 255;
  const float* xb = x + (((size_t)b * NSEQ) + (size_t)g * 8) * 2048;
  const int tid = threadIdx.x;
  float sq[8] = {0.f, 0.f, 0.f, 0.f, 0.f, 0.f, 0.f, 0.f};
  float pp[8] = {0.f, 0.f, 0.f, 0.f, 0.f, 0.f, 0.f, 0.f};
  for (int c = tid * 4; c < 2048; c += 1024) {
    float4 w4 = *(const float4*)(wv + c);
    float wj[4] = {w4.x, w4.y, w4.z, w4.w};
    float xv[8][4];
#pragma unroll
    for (int r = 0; r < 8; ++r) {
      float4 t = *(const float4*)(xb + (size_t)r * 2048 + c);
      xv[r][0] = t.x; xv[r][1] = t.y; xv[r][2] = t.z; xv[r][3] = t.w;
    }
#pragma unroll
    for (int j = 0; j < 4; ++j) {
      float x0 = xv[0][j], x1 = xv[1][j], x2 = xv[2][j], x3 = xv[3][j];
      float x4 = xv[4][j], x5 = xv[5][j], x6 = xv[6][j], x7 = xv[7][j];
      float t01 = x0 + x1, t23 = x2 + x3, t45 = x4 + x5, t67 = x6 + x7;
      float a = t01 + t23, bb = t45 + t67;
      float c3 = a + bb, d3 = a - bb, d2a = t01 - t23, d2b = t45 - t67;
      float d10 = x0 - x1, d11 = x2 - x3, d12 = x4 - x5, d13 = x6 - x7;
      sq[0] += c3 * c3;  sq[1] += d3 * d3;  sq[2] += d2a * d2a; sq[3] += d2b * d2b;
      sq[4] += d10 * d10; sq[5] += d11 * d11; sq[6] += d12 * d12; sq[7] += d13 * d13;
      float w = wj[j];
      pp[0] += x0 * w; pp[1] += x1 * w; pp[2] += x2 * w; pp[3] += x3 * w;
      pp[4] += x4 * w; pp[5] += x5 * w; pp[6] += x6 * w; pp[7] += x7 * w;
    }
  }
  __shared__ float sred[4][16];
  float vals[16];
#pragma unroll
  for (int q = 0; q < 8; ++q) vals[q] = sq[q];
#pragma unroll
  for (int q = 0; q < 8; ++q) vals[8 + q] = pp[q];
#pragma unroll
  for (int q = 0; q < 16; ++q) vals[q] = wave_sum(vals[q]);
  int lane = tid & 63, wid = tid >> 6;
  if (lane == 0) {
#pragma unroll
    for (int q = 0; q < 16; ++q) sred[wid][q] = vals[q];
  }
  __syncthreads();
  if (tid < 16) {
    float s = sred[0][tid] + sred[1][tid] + sred[2][tid] + sred[3][tid];
    if (tid < 8) {
      float scale = (tid < 2) ? 0.125f : ((tid < 4) ? 0.25f : 0.5f);
      int pos = (tid == 0) ? g : (tid == 1) ? (256 + g)
               : (tid < 4) ? (512 + 2 * g + (tid - 2)) : (1024 + 4 * g + (tid - 4));
      rho_us[b * NSEQ + pos] = sqrtf(s * scale);
    } else {
      pt[b * NSEQ + 8 * g + (tid - 8)] = s;
    }
  }
}

// ---------- kernel B: serial dynamics; 512 threads, 4 contiguous elems/thread ----------
__global__ __launch_bounds__(NT) void kB(const float* __restrict__ rho_us,
                                         const float* __restrict__ pt,
                                         const float* __restrict__ phi,
                                         float* __restrict__ rho_f) {
  __shared__ float cb[NSEQ];                    // conv staging (single buffer)
  __shared__ float up0M[NSEQ];                  // up0 = leray(grad1 v), cached in LDS
  __shared__ float vE0[NT];
  __shared__ float rhoE0[NT], rhoE3[NT];        // hold UNNORMALIZED tl during reaction
  __shared__ float upE3[NT];
  __shared__ float yE0[3][NT], yE3[3][NT];
  __shared__ float4 pairE[2][NT];               // (sgw0,sg0,sgw3,sg3), by h-parity
  __shared__ float red[256];
  __shared__ float red2[16];                    // [0..7] max partials, [8..15] dtbar partials
  __shared__ int   tieBufI[NSEQ];               // tie list: pos | (sign<<16)
  __shared__ int   tieCnt;

  const int tid = threadIdx.x;
  const int b = blockIdx.x;
  const int tm1 = (tid - 1) & (NT - 1);
  const int tp1 = (tid + 1) & (NT - 1);
  int gen = 0;
  const float CFL_ = 0.4f;

  if (tid == 0) tieCnt = 0;

  // reaction only ever needs exp(-0.1*phi): hoist it.
  float4 phv = *(const float4*)(phi + 4 * tid);
  float ephi[4] = {__expf(-0.1f * phv.x), __expf(-0.1f * phv.y),
                   __expf(-0.1f * phv.z), __expf(-0.1f * phv.w)};

  // ---- v = normalize(|dwt1d(per_token)| * sqrt(D)) ----
  // vE0 published UNNORMALIZED before the sum barrier; consumer multiplies by inv.
  float v_r[4]; float vp4c;
  {
    const float* ptb = pt + b * NSEQ;
    float vl[4]; float part = 0.f;
#pragma unroll
    for (int j = 0; j < 4; ++j) {
      float c;
      if (tid < 64) {
        int r = (4 * tid + j) * 8;
        float t01 = ptb[r] + ptb[r+1], t23 = ptb[r+2] + ptb[r+3];
        float t45 = ptb[r+4] + ptb[r+5], t67 = ptb[r+6] + ptb[r+7];
        c = ((t01 + t23) + (t45 + t67)) * INV2R2;
      } else if (tid < 128) {
        int r = (4 * (tid - 64) + j) * 8;
        float t01 = ptb[r] + ptb[r+1], t23 = ptb[r+2] + ptb[r+3];
        float t45 = ptb[r+4] + ptb[r+5], t67 = ptb[r+6] + ptb[r+7];
        c = ((t01 + t23) - (t45 + t67)) * INV2R2;
      } else if (tid < 256) {
        int r = (4 * (tid - 128) + j) * 4;
        c = ((ptb[r] + ptb[r+1]) - (ptb[r+2] + ptb[r+3])) * 0.5f;
      } else {
        int r = (4 * (tid - 256) + j) * 2;
        c = (ptb[r] - ptb[r+1]) * INVR2;
      }
      float val = SQRT2048 * fabsf(c) + EPSF;
      vl[j] = val; part += val;
    }
    vE0[tid] = vl[0];                       // unnormalized; published by sum barrier
    float sv = block_sum(part, red, tid, gen);
    float inv = 1.0f / sv;
#pragma unroll
    for (int j = 0; j < 4; ++j) v_r[j] = vl[j] * inv;
    vp4c = vE0[tp1] * inv;                  // normalized neighbor, same math
  }
  // ---- rho (UNNORMALIZED: rho_us+eps; uniform scale cancels through reaction) ----
  float rho_r[4];
  {
    float4 rv = *(const float4*)(rho_us + b * NSEQ + 4 * tid);
    rho_r[0] = rv.x + EPSF; rho_r[1] = rv.y + EPSF;
    rho_r[2] = rv.z + EPSF; rho_r[3] = rv.w + EPSF;
  }

  // ---- up0 = leray(grad1(v)) : computed ONCE, cached in LDS for every outer k ----
  float up_r[4];
  float mx, mx0, um1c;
  {
    float u0[4] = {v_r[1] - v_r[0], v_r[2] - v_r[1], v_r[3] - v_r[2], vp4c - v_r[3]};
    conv65(u0, up_r, cb, tid);
    *(float4*)(up0M + (tid << 2)) = make_float4(up_r[0], up_r[1], up_r[2], up_r[3]);
    float mm = fmaxf(fmaxf(fabsf(up_r[0]), fabsf(up_r[1])),
                     fmaxf(fabsf(up_r[2]), fabsf(up_r[3])));
    mm = wave_max(mm);
    if ((tid & 63) == 0) red2[tid >> 6] = mm;
    __syncthreads();
    float4 r2a = *(float4*)(red2), r2b = *(float4*)(red2 + 4);
    mx = rfl(fmaxf(fmaxf(fmaxf(r2a.x, r2a.y), fmaxf(r2a.z, r2a.w)),
                   fmaxf(fmaxf(r2b.x, r2b.y), fmaxf(r2b.z, r2b.w))));
    um1c = up0M[(4 * tid - 1) & (NSEQ - 1)];
    mx0 = mx;
  }

  for (int k = 0; k < 3; ++k) {
    // ---- reaction on (possibly unnormalized) rho: normalize(r^0.9 * ephi) ----
    float rhom1, rhop4;
    {
      float tl[4]; float part = 0.f;
#pragma unroll
      for (int j = 0; j < 4; ++j) {
        float r = rho_r[j];
        float t = r * ephi[j] * __expf(-0.1f * __logf(r));
        float t2 = fabsf(t) + EPSF;
        tl[j] = t2; part += t2;
      }
      rhoE0[tid] = tl[0]; rhoE3[tid] = tl[3];    // published by the sum barrier
      float s = block_sum(part, red, tid, gen);
      float inv = 1.f / s;
#pragma unroll
      for (int j = 0; j < 4; ++j) rho_r[j] = tl[j] * inv;
      rhom1 = rhoE3[tm1] * inv;                  // identical math to neighbor's rho
      rhop4 = rhoE0[tp1] * inv;
    }
    if (k > 0) {                           // u = grad1(v) identical every k -> reuse up0
      float4 u4 = *(const float4*)(up0M + (tid << 2));
      up_r[0] = u4.x; up_r[1] = u4.y; up_r[2] = u4.z; up_r[3] = u4.w;
      um1c = up0M[(4 * tid - 1) & (NSEQ - 1)];
      mx = mx0;
    }

    float y_r[4][4];
    for (int step = 0; step < 5; ++step) {
      float dt = CFL_ / (mx + EPSF);
      // ---- forward rollout (ntie in h=0, cost-dot in h=3, passA(3) mirrored) ----
      float sarr[4]; float spv = 1.f; float ntie = 1.f, dot = 0.f;
#pragma unroll
      for (int h = 0; h < 4; ++h) {
        float invp = 1.f / spv;
        float rr[6];
        if (h == 0) {
          rr[0] = rhom1; rr[1] = rho_r[0]; rr[2] = rho_r[1];
          rr[3] = rho_r[2]; rr[4] = rho_r[3]; rr[5] = rhop4;
        } else {
          rr[0] = (fabsf(yE3[h-1][tm1]) + EPSF) * invp;
#pragma unroll
          for (int j = 0; j < 4; ++j) rr[j+1] = (fabsf(y_r[h-1][j]) + EPSF) * invp;
          rr[5] = (fabsf(yE0[h-1][tp1]) + EPSF) * invp;
        }
        float part2 = 0.f, aux = 0.f;
#pragma unroll
        for (int j = 0; j < 4; ++j) {
          float ri = rr[j+1], rim1 = rr[j], rip1 = rr[j+2];
          float ui = up_r[j], um = j ? up_r[j-1] : um1c;
          float Fi = ui > 0.f ? ui * ri : ui * rip1;
          float Fm = um > 0.f ? um * rim1 : um * ri;
          float yv = ri - dt * (Fi - Fm);
          y_r[h][j] = yv;
          float ayv = fabsf(yv) + EPSF;
          part2 += ayv;
          if (h == 0) aux += (fabsf(ui) == mx) ? 1.f : 0.f;
          if (h == 3) aux += (1.f - v_r[j]) * 0.125f * ayv;
        }
        if (h < 3) { yE0[h][tid] = y_r[h][0]; yE3[h][tid] = y_r[h][3]; }
        if (h == 3) {
          float sg0 = sgnf(y_r[3][0]), sg3 = sgnf(y_r[3][3]);
          pairE[1][tid] = make_float4(sg0 * (1.f - v_r[0]) * 0.125f, sg0,
                                      sg3 * (1.f - v_r[3]) * 0.125f, sg3);
        }
        if (h == 0) { float o1, o2; block_sum2(part2, aux, red, tid, gen, o1, o2); sarr[0] = o1; ntie = o2; }
        else if (h == 3) { float o1, o2; block_sum2(part2, aux, red, tid, gen, o1, o2); sarr[3] = o1; dot = o2 / o1; }
        else sarr[h] = block_sum(part2, red, tid, gen);
        spv = sarr[h];
      }
      // ---- backward (passA folded into dot barriers via pairE mirrors) ----
      float wreg[4], upbar[4];
#pragma unroll
      for (int j = 0; j < 4; ++j) { wreg[j] = (1.f - v_r[j]) * 0.125f; upbar[j] = 0.f; }
      float dtb_part = 0.f;
#pragma unroll
      for (int h = 3; h >= 0; --h) {
        float invst = 1.f / sarr[h];
        float invp = (h > 0) ? 1.f / sarr[h-1] : 0.f;
        const int bo = h & 1;
        float yb_r[4];
#pragma unroll
        for (int j = 0; j < 4; ++j)
          yb_r[j] = sgnf(y_r[h][j]) * (wreg[j] - dot) * invst;
        float4 pm = pairE[bo][tm1], pp = pairE[bo][tp1];
        float ybm1 = (pm.z - dot * pm.w) * invst;
        float ybp4 = (pp.x - dot * pp.y) * invst;
        float rr[6];
        if (h == 0) {
          rr[0] = rhom1; rr[1] = rho_r[0]; rr[2] = rho_r[1];
          rr[3] = rho_r[2]; rr[4] = rho_r[3]; rr[5] = rhop4;
        } else {
          rr[0] = (fabsf(yE3[h-1][tm1]) + EPSF) * invp;
#pragma unroll
          for (int j = 0; j < 4; ++j) rr[j+1] = (fabsf(y_r[h-1][j]) + EPSF) * invp;
          rr[5] = (fabsf(yE0[h-1][tp1]) + EPSF) * invp;
        }
        float dotn = 0.f;
#pragma unroll
        for (int j = 0; j < 4; ++j) {
          float ri = rr[j+1], rim1 = rr[j], rip1 = rr[j+2];
          float ui = up_r[j], um = j ? up_r[j-1] : um1c;
          float ybi = yb_r[j];
          float ybm = j ? yb_r[j-1] : ybm1;
          float ybp = (j < 3) ? yb_r[j+1] : ybp4;
          float Fbi = dt * (ybp - ybi);
          float Fbm = dt * (ybi - ybm);
          float wn = ybi;
          if (ui > 0.f)    wn += Fbi * ui;
          if (!(um > 0.f)) wn += Fbm * um;
          upbar[j] += Fbi * (ui > 0.f ? ri : rip1);
          float Fi = ui > 0.f ? ui * ri : ui * rip1;
          float Fm = um > 0.f ? um * rim1 : um * ri;
          dtb_part -= ybi * (Fi - Fm);
          if (h > 0) dotn += wn * ri;
          wreg[j] = wn;
        }
        if (h > 0) {
          float sgA = sgnf(y_r[h-1][0]), sgB = sgnf(y_r[h-1][3]);
          pairE[(h - 1) & 1][tid] = make_float4(sgA * wreg[0], sgA, sgB * wreg[3], sgB);
          dot = block_sum(dotn, red, tid, gen);
        }
      }
      // ---- stage phase: cb <- upbar (pre-tie), dtbar partials, tie list ----
      *(float4*)(cb + (tid << 2)) = make_float4(upbar[0], upbar[1], upbar[2], upbar[3]);
      {
        float w = wave_sum(dtb_part);
        if ((tid & 63) == 0) red2[8 + (tid >> 6)] = w;
      }
#pragma unroll
      for (int j = 0; j < 4; ++j) {
        float ui = up_r[j];
        if (fabsf(ui) == mx) {
          int ix = atomicAdd(&tieCnt, 1);
          tieBufI[ix] = (4 * tid + j) | ((ui < 0.f) ? 0x10000 : 0);
        }
      }
      __syncthreads();
      // ---- conv-read phase: conv(LK2, upbar_pre) + tiesc * conv(LK2, T) ----
      float4 r2c = *(float4*)(red2 + 8), r2d = *(float4*)(red2 + 12);
      float dtbar = rfl(((r2c.x + r2c.y) + (r2c.z + r2c.w)) +
                        ((r2d.x + r2d.y) + (r2d.z + r2d.w)));
      float md = mx + EPSF;
      float tiesc = (dtbar * (-CFL_ / (md * md))) / ntie;
      float accv[4];
      conv81_read(accv, cb, tid);
      int nt = (int)(ntie + 0.5f);
      for (int e = 0; e < nt; ++e) {
        int ent = tieBufI[e];
        int p = ent & 0xFFFF;
        float sg = (ent & 0x10000) ? -tiesc : tiesc;
#pragma unroll
        for (int j = 0; j < 4; ++j) {
          int d = ((4 * tid + j) - p) & (NSEQ - 1);
          int ds = (d >= 1024) ? d - 2048 : d;
          if (ds >= -40 && ds <= 40) accv[j] = fmaf(sg, TAPS.lk2[ds + 40], accv[j]);
        }
      }
#pragma unroll
      for (int j = 0; j < 4; ++j) up_r[j] -= 0.1f * accv[j];
      upE3[tid] = up_r[3];
      {
        float mm = fmaxf(fmaxf(fabsf(up_r[0]), fabsf(up_r[1])),
                         fmaxf(fabsf(up_r[2]), fabsf(up_r[3])));
        mm = wave_max(mm);
        if ((tid & 63) == 0) red2[tid >> 6] = mm;
      }
      if (tid == 0) tieCnt = 0;
      __syncthreads();
      float4 r2a = *(float4*)(red2), r2b = *(float4*)(red2 + 4);
      mx = rfl(fmaxf(fmaxf(fmaxf(r2a.x, r2a.y), fmaxf(r2a.z, r2a.w)),
                     fmaxf(fmaxf(r2b.x, r2b.y), fmaxf(r2b.z, r2b.w))));
      um1c = upE3[tm1];
    }
    // ---- outer: up already = leray(u_final); advect; normalize only at k=2 ----
    float dt = CFL_ / (mx + EPSF);
    float kap = (k == 0) ? 0.01f : ((k == 1) ? 0.005f : 0.0f);
    float rr[6];
    rr[0] = rhom1; rr[1] = rho_r[0]; rr[2] = rho_r[1];
    rr[3] = rho_r[2]; rr[4] = rho_r[3]; rr[5] = rhop4;
    float ylc[4]; float p2 = 0.f;
#pragma unroll
    for (int j = 0; j < 4; ++j) {
      float ri = rr[j+1], rim1 = rr[j], rip1 = rr[j+2];
      float ui = up_r[j], um = j ? up_r[j-1] : um1c;
      float Fi = ui > 0.f ? ui * ri : ui * rip1;
      float Fm = um > 0.f ? um * rim1 : um * ri;
      float yv = ri - dt * (Fi - Fm) + kap * dt * (rip1 + rim1 - 2.f * ri);
      ylc[j] = yv; p2 += fabsf(yv) + EPSF;
    }
    if (k == 2) {          // final rho must be truly normalized
      float s = block_sum(p2, red, tid, gen);
      float inv = 1.f / s;
#pragma unroll
      for (int j = 0; j < 4; ++j) rho_r[j] = (fabsf(ylc[j]) + EPSF) * inv;
    } else {               // scale cancels through the next reaction's normalize
#pragma unroll
      for (int j = 0; j < 4; ++j) rho_r[j] = fabsf(ylc[j]) + EPSF;
    }
  }
  // ---- final: rho_f = (rho + 0.1 v)/sum ----
  {
    float fl[4]; float part = 0.f;
#pragma unroll
    for (int j = 0; j < 4; ++j) {
      float f = rho_r[j] + 0.1f * v_r[j];
      fl[j] = f; part += f;
    }
    float s = block_sum(part, red, tid, gen);
    float inv = 1.f / s;
    *(float4*)(rho_f + b * NSEQ + 4 * tid) =
        make_float4(fl[0] * inv, fl[1] * inv, fl[2] * inv, fl[3] * inv);
  }
}

// ---------- kernel C: out = IDWT3(rho_f[:,:,None] * band_w[BAND_IDX]) ----------
__global__ __launch_bounds__(256) void kC(const float* __restrict__ rho_f,
                                          const float* __restrict__ bw,
                                          float* __restrict__ out) {
  const int blk = blockIdx.x;
  const int b = blk >> 8;
  const int g = blk & 255;
  __shared__ float q[8];
  if (threadIdx.x < 8) {
    int t = threadIdx.x;
    const float* rb = rho_f + b * NSEQ;
    float val;
    if (t == 0)      val = rb[g] * INV2R2;
    else if (t == 1) val = rb[256 + g] * INV2R2;
    else if (t < 4)  val = rb[512 + 2 * g + (t - 2)] * 0.5f;
    else             val = rb[1024 + 4 * g + (t - 4)] * INVR2;
    q[t] = val;
  }
  __syncthreads();
  float* ob = out + (((size_t)b * NSEQ) + (size_t)g * 8) * 2048;
  for (int c = threadIdx.x * 4; c < 2048; c += 1024) {
    float4 B0 = *(const float4*)(bw + c);
    float4 B1 = *(const float4*)(bw + 2048 + c);
    float4 B2 = *(const float4*)(bw + 4096 + c);
    float4 B3 = *(const float4*)(bw + 6144 + c);
    float b0[4] = {B0.x, B0.y, B0.z, B0.w};
    float b1[4] = {B1.x, B1.y, B1.z, B1.w};
    float b2[4] = {B2.x, B2.y, B2.z, B2.w};
    float b3[4] = {B3.x, B3.y, B3.z, B3.w};
    float o[8][4];
#pragma unroll
    for (int cc = 0; cc < 4; ++cc) {
      float pa = q[0] * b0[cc], pd3 = q[1] * b1[cc];
      float p2a = q[2] * b2[cc], p2b = q[3] * b2[cc];
      float e0 = pa + pd3, e1 = pa - pd3;
      float f0 = e0 + p2a, f1 = e0 - p2a, f2 = e1 + p2b, f3 = e1 - p2b;
      float g0 = q[4] * b3[cc], g1 = q[5] * b3[cc], g2 = q[6] * b3[cc], g3 = q[7] * b3[cc];
      o[0][cc] = f0 + g0; o[1][cc] = f0 - g0;
      o[2][cc] = f1 + g1; o[3][cc] = f1 - g1;
      o[4][cc] = f2 + g2; o[5][cc] = f2 - g2;
      o[6][cc] = f3 + g3; o[7][cc] = f3 - g3;
    }
#pragma unroll
    for (int j = 0; j < 8; ++j) {
      float4 t = make_float4(o[j][0], o[j][1], o[j][2], o[j][3]);
      *(float4*)(ob + (size_t)j * 2048 + c) = t;
    }
  }
}

extern "C" void kernel_launch(void* const* d_in, const int* in_sizes, int n_in,
                              void* d_out, int out_size, void* d_ws, size_t ws_size,
                              hipStream_t stream) {
  (void)in_sizes; (void)n_in; (void)out_size; (void)ws_size;
  const float* x   = (const float*)d_in[0];
  const float* wv  = (const float*)d_in[1];
  const float* phi = (const float*)d_in[2];
  const float* bw  = (const float*)d_in[3];
  float* out = (float*)d_out;
  float* rho_us = (float*)d_ws;
  float* pt     = rho_us + 8 * NSEQ;
  float* rho_f  = pt + 8 * NSEQ;

  kA<<<dim3(2048), dim3(256), 0, stream>>>(x, wv, rho_us, pt);
  kB<<<dim3(8), dim3(NT), 0, stream>>>(rho_us, pt, phi, rho_f);
  kC<<<dim3(2048), dim3(256), 0, stream>>>(rho_f, bw, out);
}